// Round 2
// baseline (1248.653 us; speedup 1.0000x reference)
//
#include <hip/hip_runtime.h>

#define N_PTS 81920
#define M_PTS 20000
#define NC 13
#define NCELLS 2197
#define CELLW 0.7692307692f
#define INVCELL 1.3f
#define BIGF 3.0e38f
#define CAND_CAP 768

__device__ __forceinline__ int clampi(int v, int lo, int hi) {
  return v < lo ? lo : (v > hi ? hi : v);
}
__device__ __forceinline__ int cell_coord(float p) {
  return clampi((int)(p * INVCELL), 0, NC - 1);
}

// ---- setup kernels (fused x/y variants) ----

__global__ void hist_both_kernel(const float* __restrict__ y, const float* __restrict__ x,
                                 int* __restrict__ ycnt, int* __restrict__ xcnt) {
  int i = blockIdx.x * blockDim.x + threadIdx.x;
  if (i < M_PTS) {
    int c = (cell_coord(y[3*i+2])*NC + cell_coord(y[3*i+1]))*NC + cell_coord(y[3*i]);
    atomicAdd(&ycnt[c], 1);
  } else {
    int j = i - M_PTS;
    if (j < N_PTS) {
      int c = (cell_coord(x[3*j+2])*NC + cell_coord(x[3*j+1]))*NC + cell_coord(x[3*j]);
      atomicAdd(&xcnt[c], 1);
    }
  }
}

__global__ void scan2_kernel(const int* __restrict__ ycnt, int* __restrict__ ystart, int* __restrict__ ycur,
                             const int* __restrict__ xcnt, int* __restrict__ xstart, int* __restrict__ xcur) {
  const int* cnt = (blockIdx.x == 0) ? ycnt : xcnt;
  int* start     = (blockIdx.x == 0) ? ystart : xstart;
  int* cursor    = (blockIdx.x == 0) ? ycur : xcur;
  __shared__ int tmp[1024];
  int tid = threadIdx.x;
  int chunk = (NCELLS + 1023) >> 10;
  int base = tid * chunk;
  int sum = 0;
  for (int k = 0; k < chunk; ++k) {
    int j = base + k;
    if (j < NCELLS) sum += cnt[j];
  }
  tmp[tid] = sum;
  __syncthreads();
  for (int off = 1; off < 1024; off <<= 1) {
    int v = (tid >= off) ? tmp[tid - off] : 0;
    __syncthreads();
    tmp[tid] += v;
    __syncthreads();
  }
  int run = tmp[tid] - sum;
  for (int k = 0; k < chunk; ++k) {
    int j = base + k;
    if (j < NCELLS) { start[j] = run; cursor[j] = run; run += cnt[j]; }
  }
  if (tid == 1023) start[NCELLS] = tmp[1023];
}

__global__ void scatter_both_kernel(const float* __restrict__ y, const float* __restrict__ x,
                                    int* __restrict__ ycur, int* __restrict__ xcur,
                                    float4* __restrict__ ys4, int* __restrict__ xorder) {
  int i = blockIdx.x * blockDim.x + threadIdx.x;
  if (i < M_PTS) {
    float px = y[3*i], py = y[3*i+1], pz = y[3*i+2];
    int c = (cell_coord(pz)*NC + cell_coord(py))*NC + cell_coord(px);
    int pos = atomicAdd(&ycur[c], 1);
    ys4[pos] = make_float4(px, py, pz, __int_as_float(i));
  } else {
    int j = i - M_PTS;
    if (j < N_PTS) {
      int c = (cell_coord(x[3*j+2])*NC + cell_coord(x[3*j+1]))*NC + cell_coord(x[3*j]);
      int pos = atomicAdd(&xcur[c], 1);
      xorder[pos] = j;
    }
  }
}

// determinism: in-cell sort of ys4 by original index (atomic scatter order varies)
__global__ void sortcell_kernel(float4* __restrict__ ys4, const int* __restrict__ ystart) {
  int c = blockIdx.x * blockDim.x + threadIdx.x;
  if (c >= NCELLS) return;
  int r0 = ystart[c], r1 = ystart[c+1];
  for (int i = r0 + 1; i < r1; ++i) {
    float4 v = ys4[i];
    int key = __float_as_int(v.w);
    int j = i - 1;
    while (j >= r0 && __float_as_int(ys4[j].w) > key) { ys4[j+1] = ys4[j]; --j; }
    ys4[j+1] = v;
  }
}

// ---- shared helpers ----

// wlds layout (floats): W1t[16][20] (i incl. invd row), W2t[16][16]@320,
// W3t[16][32]@576, b1@1088, b2@1104, b3@1120, S1@1136, T1@1152, S2@1168, T2@1184
__device__ __forceinline__ void stage_weights(float* lds, int t,
    const float* W1, const float* b1, const float* W2, const float* b2,
    const float* W3, const float* b3,
    const float* g1, const float* be1, const float* m1, const float* v1,
    const float* g2, const float* be2, const float* m2, const float* v2)
{
  for (int k = t; k < 272; k += 256) { int i = k >> 4, o = k & 15; lds[o*20 + i] = W1[k]; }
  for (int k = t; k < 256; k += 256) { int i = k >> 4, o = k & 15; lds[320 + o*16 + i] = W2[k]; }
  for (int k = t; k < 512; k += 256) { int i = k >> 4, o = k & 15; lds[576 + o*32 + i] = W3[k]; }
  if (t < 16) {
    lds[1088 + t] = b1[t];
    lds[1104 + t] = b2[t];
    lds[1120 + t] = b3[t];
    float s1 = g1[t] * rsqrtf(v1[t] + 1e-5f);
    lds[1136 + t] = s1;
    lds[1152 + t] = be1[t] - m1[t]*s1;
    float s2 = g2[t] * rsqrtf(v2[t] + 1e-5f);
    lds[1168 + t] = s2;
    lds[1184 + t] = be2[t] - m2[t]*s2;
  }
}

// sorted top-16 insert, fully unrolled; caller guarantees d < s[15]
__device__ __forceinline__ void topk_insert(float (&s)[16], int (&si)[16], float d, int qi) {
  #pragma unroll
  for (int j = 15; j >= 1; --j) {
    bool c1 = d < s[j-1];
    bool c2 = d < s[j];
    float ns = c1 ? s[j-1] : (c2 ? d : s[j]);
    int  ni = c1 ? si[j-1] : (c2 ? qi : si[j]);
    s[j] = ns; si[j] = ni;
  }
  if (d < s[0]) { si[0] = qi; s[0] = d; }
}

// exact 16th-smallest threshold over the 4 sub-lists of a group:
// smallest uint T with #(d_bits < T) >= 16  (d >= 0 so float bits are monotone)
__device__ __forceinline__ unsigned bisect16(const float (&s)[16]) {
  unsigned lo = 0u, hi = 0x7f800000u;   // count(inf) >= 16 guaranteed (>=246 real cands)
  while (hi - lo > 1u) {
    unsigned mid = (lo + hi) >> 1;
    int c = 0;
    #pragma unroll
    for (int j = 0; j < 16; ++j) c += (__float_as_uint(s[j]) < mid) ? 1 : 0;
    c += __shfl_xor(c, 1);
    c += __shfl_xor(c, 2);
    if (c >= 16) hi = mid; else lo = mid;
  }
  return hi;
}

// ---- main fused kernel: block-per-cell, TPP=4, LDS-staged candidates ----
__global__ void __launch_bounds__(256, 4) knn_mlp_kernel(
    const float* __restrict__ x, const float* __restrict__ yat,
    const float* __restrict__ W1, const float* __restrict__ b1,
    const float* __restrict__ W2, const float* __restrict__ b2,
    const float* __restrict__ W3, const float* __restrict__ b3,
    const float* __restrict__ g1, const float* __restrict__ be1,
    const float* __restrict__ m1, const float* __restrict__ v1,
    const float* __restrict__ g2, const float* __restrict__ be2,
    const float* __restrict__ m2, const float* __restrict__ v2,
    const float4* __restrict__ ys4, const int* __restrict__ ystart,
    const int* __restrict__ xorder, const int* __restrict__ xstart,
    float* __restrict__ out)
{
  __shared__ float wlds[1200];
  __shared__ float4 cand[CAND_CAP];
  __shared__ float2 merged[64][17];   // stride 17 pads bank pattern

  int t = threadIdx.x;
  stage_weights(wlds, t, W1,b1,W2,b2,W3,b3, g1,be1,m1,v1, g2,be2,m2,v2);

  int c = blockIdx.x;
  int ccx = c % NC, ccy = (c / NC) % NC, ccz = c / (NC*NC);
  int pbeg = xstart[c];
  int cnt  = xstart[c+1] - pbeg;

  int z0 = ccz-1 < 0 ? 0 : ccz-1, z1 = ccz+1 > NC-1 ? NC-1 : ccz+1;
  int y0 = ccy-1 < 0 ? 0 : ccy-1, y1 = ccy+1 > NC-1 ? NC-1 : ccy+1;
  int x0 = ccx-1 < 0 ? 0 : ccx-1, x1 = ccx+1 > NC-1 ? NC-1 : ccx+1;

  // stage 3x3x3 (clamped) region into LDS; rows are contiguous ys4 slices
  int off = 0; bool ok = true;
  #pragma unroll
  for (int dz2 = 0; dz2 < 3; ++dz2) {
    int gz = z0 + dz2;
    if (gz <= z1) {
      #pragma unroll
      for (int dy2 = 0; dy2 < 3; ++dy2) {
        int gy = y0 + dy2;
        if (gy <= y1) {
          int rowbase = (gz*NC + gy)*NC;
          int r0 = ystart[rowbase + x0];
          int len = ystart[rowbase + x1 + 1] - r0;
          if (ok && off + len <= CAND_CAP) {
            for (int k = t; k < len; k += 256) cand[off + k] = ys4[r0 + k];
            off += len;
          } else ok = false;
        }
      }
    }
  }
  int L = off;
  __syncthreads();
  if (cnt == 0) return;

  int g = t >> 2, sub = t & 3;
  int lanebase = (t & 63) & ~3;

  for (int base = 0; base < cnt; base += 64) {
    int np = cnt - base; if (np > 64) np = 64;
    if (g < np) {
      int p = xorder[pbeg + base + g];
      float xpx = x[3*p], xpy = x[3*p+1], xpz = x[3*p+2];

      float s[16]; int si[16];
      #pragma unroll
      for (int j = 0; j < 16; ++j) { s[j] = BIGF; si[j] = 0; }

      // scan staged candidates, stride-4 per sub-thread (64B broadcast reads)
      for (int k = sub; k < L; k += 4) {
        float4 q = cand[k];
        float dx = xpx - q.x, dy = xpy - q.y, dz = xpz - q.z;
        float d = fmaf(dx, dx, fmaf(dy, dy, dz*dz));
        if (d < s[15]) topk_insert(s, si, d, __float_as_int(q.w));
      }

      auto scan_row_g = [&](int gz, int gy, int xa, int xb) {
        int rowbase = (gz*NC + gy)*NC;
        int r0 = ystart[rowbase + xa];
        int r1 = ystart[rowbase + xb + 1];
        for (int i = r0 + sub; i < r1; i += 4) {
          float4 q = ys4[i];
          float dx = xpx - q.x, dy = xpy - q.y, dz = xpz - q.z;
          float d = fmaf(dx, dx, fmaf(dy, dy, dz*dz));
          if (d < s[15]) topk_insert(s, si, d, __float_as_int(q.w));
        }
      };

      if (!ok) {   // rows that didn't fit in LDS (practically never): scan from global
        int off2 = 0; bool ok2 = true;
        #pragma unroll
        for (int dz2 = 0; dz2 < 3; ++dz2) {
          int gz = z0 + dz2;
          if (gz <= z1) {
            #pragma unroll
            for (int dy2 = 0; dy2 < 3; ++dy2) {
              int gy = y0 + dy2;
              if (gy <= y1) {
                int rowbase = (gz*NC + gy)*NC;
                int len = ystart[rowbase + x1 + 1] - ystart[rowbase + x0];
                if (ok2 && off2 + len <= CAND_CAP) off2 += len;
                else { ok2 = false; scan_row_g(gz, gy, x0, x1); }
              }
            }
          }
        }
      }

      // exact group threshold (16th smallest of the 4-list union)
      unsigned T = bisect16(s);

      // ring expansion (exact); T > true_s15 so the check is conservative
      int R = 1;
      while (true) {
        float b = BIGF;
        if (ccx - R >= 0)    b = fminf(b, xpx - (float)(ccx-R)*CELLW);
        if (ccx + R <= NC-2) b = fminf(b, (float)(ccx+R+1)*CELLW - xpx);
        if (ccy - R >= 0)    b = fminf(b, xpy - (float)(ccy-R)*CELLW);
        if (ccy + R <= NC-2) b = fminf(b, (float)(ccy+R+1)*CELLW - xpy);
        if (ccz - R >= 0)    b = fminf(b, xpz - (float)(ccz-R)*CELLW);
        if (ccz + R <= NC-2) b = fminf(b, (float)(ccz+R+1)*CELLW - xpz);
        b = fmaxf(b - 1e-4f, 0.0f);
        if (__uint_as_float(T) <= b*b || R >= NC) break;
        ++R;
        int z0r = ccz-R < 0 ? 0 : ccz-R, z1r = ccz+R > NC-1 ? NC-1 : ccz+R;
        int y0r = ccy-R < 0 ? 0 : ccy-R, y1r = ccy+R > NC-1 ? NC-1 : ccy+R;
        int x0r = ccx-R < 0 ? 0 : ccx-R, x1r = ccx+R > NC-1 ? NC-1 : ccx+R;
        for (int gz = z0r; gz <= z1r; ++gz) {
          int dzz = gz - ccz; if (dzz < 0) dzz = -dzz;
          for (int gy = y0r; gy <= y1r; ++gy) {
            int dyy = gy - ccy; if (dyy < 0) dyy = -dyy;
            if (dzz == R || dyy == R) {
              scan_row_g(gz, gy, x0r, x1r);
            } else {
              if (ccx - R >= 0)    scan_row_g(gz, gy, ccx-R, ccx-R);
              if (ccx + R <= NC-1) scan_row_g(gz, gy, ccx+R, ccx+R);
            }
          }
        }
        T = bisect16(s);
      }

      // compact the group's 16 members into LDS (wave-internal, no barrier needed)
      #pragma unroll
      for (int m = 0; m < 4; ++m) merged[g][sub*4 + m] = make_float2(2.0e30f, 0.0f);

      int cm = 0;
      #pragma unroll
      for (int j = 0; j < 16; ++j) cm += (__float_as_uint(s[j]) < T) ? 1 : 0;
      int c0 = __shfl(cm, lanebase + 0);
      int c1 = __shfl(cm, lanebase + 1);
      int c2 = __shfl(cm, lanebase + 2);
      int excl = (sub > 0 ? c0 : 0) + (sub > 1 ? c1 : 0) + (sub > 2 ? c2 : 0);
      #pragma unroll
      for (int j = 0; j < 16; ++j) {
        if (j < cm) {
          int pos = excl + j;
          if (pos < 16) merged[g][pos] = make_float2(s[j], __int_as_float(si[j]));
        }
      }

      // MLP: 4 neighbors per sub-thread, then cross-lane reduce
      const float* W1t = wlds;
      const float* W2t = wlds + 320;
      const float* W3t = wlds + 576;
      const float* sb1 = wlds + 1088;
      const float* sb2 = wlds + 1104;
      const float* sb3 = wlds + 1120;
      const float* S1 = wlds + 1136;
      const float* T1 = wlds + 1152;
      const float* S2 = wlds + 1168;
      const float* T2 = wlds + 1184;

      float fx1[16], fx2[16];
      #pragma unroll
      for (int o = 0; o < 16; ++o) { fx1[o] = 0.0f; fx2[o] = 0.0f; }

      #pragma unroll 1
      for (int m = 0; m < 4; ++m) {
        float2 e = merged[g][sub*4 + m];
        if (e.x < 1.0e30f) {
          float invd = 1.0f / e.x;
          int id = __float_as_int(e.y);
          const float4* a4 = (const float4*)(yat + ((size_t)id << 4));
          float4 q0 = a4[0], q1 = a4[1], q2 = a4[2], q3 = a4[3];
          float a[16];
          a[0]=q0.x; a[1]=q0.y; a[2]=q0.z; a[3]=q0.w;
          a[4]=q1.x; a[5]=q1.y; a[6]=q1.z; a[7]=q1.w;
          a[8]=q2.x; a[9]=q2.y; a[10]=q2.z; a[11]=q2.w;
          a[12]=q3.x; a[13]=q3.y; a[14]=q3.z; a[15]=q3.w;
          float h[16];
          #pragma unroll
          for (int o = 0; o < 16; ++o) {
            float acc = fmaf(invd, W1t[o*20 + 16], sb1[o]);
            #pragma unroll
            for (int i = 0; i < 16; ++i) acc = fmaf(a[i], W1t[o*20 + i], acc);
            acc = fmaxf(acc, 0.2f * acc);
            float hv = fmaf(acc, S1[o], T1[o]);
            h[o] = hv;
            fx1[o] += hv;
          }
          #pragma unroll
          for (int o = 0; o < 16; ++o) {
            float acc = sb2[o];
            #pragma unroll
            for (int i = 0; i < 16; ++i) acc = fmaf(h[i], W2t[o*16 + i], acc);
            acc = fmaxf(acc, 0.2f * acc);
            fx2[o] += fmaf(acc, S2[o], T2[o]);
          }
        }
      }

      #pragma unroll
      for (int o = 0; o < 16; ++o) {
        fx1[o] += __shfl_xor(fx1[o], 1);
        fx1[o] += __shfl_xor(fx1[o], 2);
        fx2[o] += __shfl_xor(fx2[o], 1);
        fx2[o] += __shfl_xor(fx2[o], 2);
      }

      // each sub-thread computes 4 of the 16 outputs
      float r[4];
      #pragma unroll
      for (int oo = 0; oo < 4; ++oo) {
        int o = sub*4 + oo;
        float acc = sb3[o];
        #pragma unroll
        for (int i = 0; i < 16; ++i) acc = fmaf(fx1[i], W3t[o*32 + i], acc);
        #pragma unroll
        for (int i = 0; i < 16; ++i) acc = fmaf(fx2[i], W3t[o*32 + 16 + i], acc);
        r[oo] = acc;
      }
      float4 rv; rv.x = r[0]; rv.y = r[1]; rv.z = r[2]; rv.w = r[3];
      *(float4*)(out + ((size_t)p << 4) + sub*4) = rv;
    }
  }
}

// ---- fallback: brute force (no workspace needed) ----
__device__ __forceinline__ void mlp_and_store(const float* lds, const float2* spill, int t,
    const float* __restrict__ yat, float* __restrict__ out, int p)
{
  const float* W1t = lds;
  const float* W2t = lds + 320;
  const float* W3t = lds + 576;
  const float* sb1 = lds + 1088;
  const float* sb2 = lds + 1104;
  const float* sb3 = lds + 1120;
  const float* S1 = lds + 1136;
  const float* T1 = lds + 1152;
  const float* S2 = lds + 1168;
  const float* T2 = lds + 1184;

  float fx1[16], fx2[16];
  #pragma unroll
  for (int o = 0; o < 16; ++o) { fx1[o] = 0.0f; fx2[o] = 0.0f; }

  #pragma unroll 1
  for (int j = 0; j < 16; ++j) {
    float2 sv = spill[j*256 + t];
    float invd = 1.0f / sv.x;
    int id = __float_as_int(sv.y);
    const float4* a4 = (const float4*)(yat + ((size_t)id << 4));
    float4 q0 = a4[0], q1 = a4[1], q2 = a4[2], q3 = a4[3];
    float a[16];
    a[0]=q0.x; a[1]=q0.y; a[2]=q0.z; a[3]=q0.w;
    a[4]=q1.x; a[5]=q1.y; a[6]=q1.z; a[7]=q1.w;
    a[8]=q2.x; a[9]=q2.y; a[10]=q2.z; a[11]=q2.w;
    a[12]=q3.x; a[13]=q3.y; a[14]=q3.z; a[15]=q3.w;
    float h[16];
    #pragma unroll
    for (int o = 0; o < 16; ++o) {
      float acc = fmaf(invd, W1t[o*20 + 16], sb1[o]);
      #pragma unroll
      for (int i = 0; i < 16; ++i) acc = fmaf(a[i], W1t[o*20 + i], acc);
      acc = fmaxf(acc, 0.2f * acc);
      float hv = fmaf(acc, S1[o], T1[o]);
      h[o] = hv;
      fx1[o] += hv;
    }
    #pragma unroll
    for (int o = 0; o < 16; ++o) {
      float acc = sb2[o];
      #pragma unroll
      for (int i = 0; i < 16; ++i) acc = fmaf(h[i], W2t[o*16 + i], acc);
      acc = fmaxf(acc, 0.2f * acc);
      fx2[o] += fmaf(acc, S2[o], T2[o]);
    }
  }

  float res[16];
  #pragma unroll
  for (int o = 0; o < 16; ++o) {
    float acc = sb3[o];
    #pragma unroll
    for (int i = 0; i < 16; ++i) acc = fmaf(fx1[i], W3t[o*32 + i], acc);
    #pragma unroll
    for (int i = 0; i < 16; ++i) acc = fmaf(fx2[i], W3t[o*32 + 16 + i], acc);
    res[o] = acc;
  }
  float* op = out + ((size_t)p << 4);
  float4 r;
  r.x=res[0]; r.y=res[1]; r.z=res[2]; r.w=res[3];   ((float4*)op)[0] = r;
  r.x=res[4]; r.y=res[5]; r.z=res[6]; r.w=res[7];   ((float4*)op)[1] = r;
  r.x=res[8]; r.y=res[9]; r.z=res[10]; r.w=res[11]; ((float4*)op)[2] = r;
  r.x=res[12]; r.y=res[13]; r.z=res[14]; r.w=res[15];((float4*)op)[3] = r;
}

__global__ void __launch_bounds__(256) brute_kernel(
    const float* __restrict__ x, const float* __restrict__ y, const float* __restrict__ yat,
    const float* __restrict__ W1, const float* __restrict__ b1,
    const float* __restrict__ W2, const float* __restrict__ b2,
    const float* __restrict__ W3, const float* __restrict__ b3,
    const float* __restrict__ g1, const float* __restrict__ be1,
    const float* __restrict__ m1, const float* __restrict__ v1,
    const float* __restrict__ g2, const float* __restrict__ be2,
    const float* __restrict__ m2, const float* __restrict__ v2,
    float* __restrict__ out)
{
  __shared__ float lds[1200];
  __shared__ float2 spill[4096];
  __shared__ float4 ybuf[1024];
  int t = threadIdx.x;
  stage_weights(lds, t, W1,b1,W2,b2,W3,b3, g1,be1,m1,v1, g2,be2,m2,v2);

  int gid = blockIdx.x * 256 + t;
  float xpx = x[3*gid], xpy = x[3*gid+1], xpz = x[3*gid+2];
  float s[16]; int si[16];
  #pragma unroll
  for (int j = 0; j < 16; ++j) { s[j] = BIGF; si[j] = 0; }

  for (int base = 0; base < M_PTS; base += 1024) {
    int nload = M_PTS - base; if (nload > 1024) nload = 1024;
    __syncthreads();
    for (int k = t; k < nload; k += 256) {
      int i = base + k;
      ybuf[k] = make_float4(y[3*i], y[3*i+1], y[3*i+2], __int_as_float(i));
    }
    __syncthreads();
    for (int i2 = 0; i2 < nload; ++i2) {
      float4 q = ybuf[i2];
      float dx = xpx - q.x, dy = xpy - q.y, dz = xpz - q.z;
      float d = fmaf(dx, dx, fmaf(dy, dy, dz*dz));
      if (d < s[15]) topk_insert(s, si, d, __float_as_int(q.w));
    }
  }

  #pragma unroll
  for (int j = 0; j < 16; ++j) spill[j*256 + t] = make_float2(s[j], __int_as_float(si[j]));
  mlp_and_store(lds, spill, t, yat, out, gid);
}

extern "C" void kernel_launch(void* const* d_in, const int* in_sizes, int n_in,
                              void* d_out, int out_size, void* d_ws, size_t ws_size,
                              hipStream_t stream) {
  const float* x   = (const float*)d_in[0];
  const float* y   = (const float*)d_in[1];
  const float* yat = (const float*)d_in[2];
  const float* W1  = (const float*)d_in[5];
  const float* b1  = (const float*)d_in[6];
  const float* W2  = (const float*)d_in[7];
  const float* b2  = (const float*)d_in[8];
  const float* W3  = (const float*)d_in[9];
  const float* b3  = (const float*)d_in[10];
  const float* g1  = (const float*)d_in[11];
  const float* be1 = (const float*)d_in[12];
  const float* m1  = (const float*)d_in[13];
  const float* v1  = (const float*)d_in[14];
  const float* g2  = (const float*)d_in[15];
  const float* be2 = (const float*)d_in[16];
  const float* m2  = (const float*)d_in[17];
  const float* v2  = (const float*)d_in[18];
  float* out = (float*)d_out;

  if (ws_size >= 700480) {
    char* ws = (char*)d_ws;
    float4* ys4 = (float4*)(ws);              // M*16 = 320000 B
    int* xorder = (int*)(ws + 320000);        // N*4  = 327680 B
    int* ycnt   = (int*)(ws + 647680);        // 2197*4
    int* xcnt   = (int*)(ws + 656480);        // 2197*4
    int* ystart = (int*)(ws + 665280);        // 2198*4
    int* ycur   = (int*)(ws + 674080);        // 2197*4
    int* xstart = (int*)(ws + 682880);        // 2198*4
    int* xcur   = (int*)(ws + 691680);        // 2197*4

    hipMemsetAsync(ws + 647680, 0, 17588, stream);   // ycnt + xcnt (incl. 12B gap)
    int grid_mn = (M_PTS + N_PTS + 255) / 256;
    hist_both_kernel<<<grid_mn, 256, 0, stream>>>(y, x, ycnt, xcnt);
    scan2_kernel<<<2, 1024, 0, stream>>>(ycnt, ystart, ycur, xcnt, xstart, xcur);
    scatter_both_kernel<<<grid_mn, 256, 0, stream>>>(y, x, ycur, xcur, ys4, xorder);
    sortcell_kernel<<<(NCELLS+255)/256, 256, 0, stream>>>(ys4, ystart);
    knn_mlp_kernel<<<NCELLS, 256, 0, stream>>>(x, yat, W1,b1,W2,b2,W3,b3,
        g1,be1,m1,v1, g2,be2,m2,v2, ys4, ystart, xorder, xstart, out);
  } else {
    brute_kernel<<<N_PTS/256, 256, 0, stream>>>(x, y, yat, W1,b1,W2,b2,W3,b3,
        g1,be1,m1,v1, g2,be2,m2,v2, out);
  }
}

// Round 3
// 514.395 us; speedup vs baseline: 2.4274x; 2.4274x over previous
//
#include <hip/hip_runtime.h>

#define N_PTS 81920
#define M_PTS 20000
#define NC 13
#define NCELLS 2197
#define CELLW 0.7692307692f
#define INVCELL 1.3f
#define BIGF 3.0e38f

__device__ __forceinline__ int clampi(int v, int lo, int hi) {
  return v < lo ? lo : (v > hi ? hi : v);
}
__device__ __forceinline__ int cell_coord(float p) {
  return clampi((int)(p * INVCELL), 0, NC - 1);
}

// ---- setup kernels ----

__global__ void hist_both_kernel(const float* __restrict__ y, const float* __restrict__ x,
                                 int* __restrict__ ycnt, int* __restrict__ xcnt) {
  int i = blockIdx.x * blockDim.x + threadIdx.x;
  if (i < M_PTS) {
    int c = (cell_coord(y[3*i+2])*NC + cell_coord(y[3*i+1]))*NC + cell_coord(y[3*i]);
    atomicAdd(&ycnt[c], 1);
  } else {
    int j = i - M_PTS;
    if (j < N_PTS) {
      int c = (cell_coord(x[3*j+2])*NC + cell_coord(x[3*j+1]))*NC + cell_coord(x[3*j]);
      atomicAdd(&xcnt[c], 1);
    }
  }
}

__global__ void scan2_kernel(const int* __restrict__ ycnt, int* __restrict__ ystart, int* __restrict__ ycur,
                             const int* __restrict__ xcnt, int* __restrict__ xstart, int* __restrict__ xcur) {
  const int* cnt = (blockIdx.x == 0) ? ycnt : xcnt;
  int* start     = (blockIdx.x == 0) ? ystart : xstart;
  int* cursor    = (blockIdx.x == 0) ? ycur : xcur;
  __shared__ int tmp[1024];
  int tid = threadIdx.x;
  int chunk = (NCELLS + 1023) >> 10;
  int base = tid * chunk;
  int sum = 0;
  for (int k = 0; k < chunk; ++k) {
    int j = base + k;
    if (j < NCELLS) sum += cnt[j];
  }
  tmp[tid] = sum;
  __syncthreads();
  for (int off = 1; off < 1024; off <<= 1) {
    int v = (tid >= off) ? tmp[tid - off] : 0;
    __syncthreads();
    tmp[tid] += v;
    __syncthreads();
  }
  int run = tmp[tid] - sum;
  for (int k = 0; k < chunk; ++k) {
    int j = base + k;
    if (j < NCELLS) { start[j] = run; cursor[j] = run; run += cnt[j]; }
  }
  if (tid == 1023) start[NCELLS] = tmp[1023];
}

__global__ void scatter_both_kernel(const float* __restrict__ y, const float* __restrict__ x,
                                    int* __restrict__ ycur, int* __restrict__ xcur,
                                    float4* __restrict__ ys4, int* __restrict__ xorder) {
  int i = blockIdx.x * blockDim.x + threadIdx.x;
  if (i < M_PTS) {
    float px = y[3*i], py = y[3*i+1], pz = y[3*i+2];
    int c = (cell_coord(pz)*NC + cell_coord(py))*NC + cell_coord(px);
    int pos = atomicAdd(&ycur[c], 1);
    ys4[pos] = make_float4(px, py, pz, __int_as_float(i));
  } else {
    int j = i - M_PTS;
    if (j < N_PTS) {
      int c = (cell_coord(x[3*j+2])*NC + cell_coord(x[3*j+1]))*NC + cell_coord(x[3*j]);
      int pos = atomicAdd(&xcur[c], 1);
      xorder[pos] = j;
    }
  }
}

// determinism: in-cell sort by original index (atomic scatter order varies per run)
__global__ void sortcell_kernel(float4* __restrict__ ys4, const int* __restrict__ ystart) {
  int c = blockIdx.x * blockDim.x + threadIdx.x;
  if (c >= NCELLS) return;
  int r0 = ystart[c], r1 = ystart[c+1];
  for (int i = r0 + 1; i < r1; ++i) {
    float4 v = ys4[i];
    int key = __float_as_int(v.w);
    int j = i - 1;
    while (j >= r0 && __float_as_int(ys4[j].w) > key) { ys4[j+1] = ys4[j]; --j; }
    ys4[j+1] = v;
  }
}

// ---- shared helpers ----

// wlds layout (floats): W1t[16][20] (i incl. invd row), W2t[16][16]@320,
// W3t[16][32]@576, b1@1088, b2@1104, b3@1120, S1@1136, T1@1152, S2@1168, T2@1184
__device__ __forceinline__ void stage_weights(float* lds, int t,
    const float* W1, const float* b1, const float* W2, const float* b2,
    const float* W3, const float* b3,
    const float* g1, const float* be1, const float* m1, const float* v1,
    const float* g2, const float* be2, const float* m2, const float* v2)
{
  for (int k = t; k < 272; k += 256) { int i = k >> 4, o = k & 15; lds[o*20 + i] = W1[k]; }
  for (int k = t; k < 256; k += 256) { int i = k >> 4, o = k & 15; lds[320 + o*16 + i] = W2[k]; }
  for (int k = t; k < 512; k += 256) { int i = k >> 4, o = k & 15; lds[576 + o*32 + i] = W3[k]; }
  if (t < 16) {
    lds[1088 + t] = b1[t];
    lds[1104 + t] = b2[t];
    lds[1120 + t] = b3[t];
    float s1 = g1[t] * rsqrtf(v1[t] + 1e-5f);
    lds[1136 + t] = s1;
    lds[1152 + t] = be1[t] - m1[t]*s1;
    float s2 = g2[t] * rsqrtf(v2[t] + 1e-5f);
    lds[1168 + t] = s2;
    lds[1184 + t] = be2[t] - m2[t]*s2;
  }
}

// sorted top-16 insert, fully unrolled (static register indices only);
// caller guarantees d < s[15]
__device__ __forceinline__ void topk_insert(float (&s)[16], int (&si)[16], float d, int qi) {
  #pragma unroll
  for (int j = 15; j >= 1; --j) {
    bool c1 = d < s[j-1];
    bool c2 = d < s[j];
    float ns = c1 ? s[j-1] : (c2 ? d : s[j]);
    int  ni = c1 ? si[j-1] : (c2 ? qi : si[j]);
    s[j] = ns; si[j] = ni;
  }
  if (d < s[0]) { si[0] = qi; s[0] = d; }
}

// ---- split path kernel A: kNN only (low register pressure, no spills) ----
__global__ void __launch_bounds__(256) knn_kernel(
    const float* __restrict__ x,
    const float4* __restrict__ ys4, const int* __restrict__ ystart,
    const int* __restrict__ xorder,
    float* __restrict__ pd, unsigned short* __restrict__ pi)
{
  int gid = blockIdx.x * 256 + threadIdx.x;   // grid exactly N_PTS/256
  int p = xorder[gid];
  float xpx = x[3*p], xpy = x[3*p+1], xpz = x[3*p+2];
  int cx = cell_coord(xpx), cy = cell_coord(xpy), cz = cell_coord(xpz);

  float s[16]; int si[16];
  #pragma unroll
  for (int j = 0; j < 16; ++j) { s[j] = BIGF; si[j] = 0; }

  auto scan_row = [&](int gz, int gy, int xa, int xb) {
    int rowbase = (gz*NC + gy)*NC;
    int r0 = ystart[rowbase + xa];
    int r1 = ystart[rowbase + xb + 1];
    int i = r0;
    for (; i + 2 <= r1; i += 2) {
      float4 q0 = ys4[i];
      float4 q1 = ys4[i+1];
      float dx0 = xpx - q0.x, dy0 = xpy - q0.y, dz0 = xpz - q0.z;
      float dx1 = xpx - q1.x, dy1 = xpy - q1.y, dz1 = xpz - q1.z;
      float d0 = fmaf(dx0, dx0, fmaf(dy0, dy0, dz0*dz0));
      float d1 = fmaf(dx1, dx1, fmaf(dy1, dy1, dz1*dz1));
      if (d0 < s[15]) topk_insert(s, si, d0, __float_as_int(q0.w));
      if (d1 < s[15]) topk_insert(s, si, d1, __float_as_int(q1.w));
    }
    if (i < r1) {
      float4 q = ys4[i];
      float dx = xpx - q.x, dy = xpy - q.y, dz = xpz - q.z;
      float d = fmaf(dx, dx, fmaf(dy, dy, dz*dz));
      if (d < s[15]) topk_insert(s, si, d, __float_as_int(q.w));
    }
  };

  { // initial 3x3x3 (clamped); contiguous x-cells scanned as one range
    int z0 = cz-1 < 0 ? 0 : cz-1, z1 = cz+1 > NC-1 ? NC-1 : cz+1;
    int y0 = cy-1 < 0 ? 0 : cy-1, y1 = cy+1 > NC-1 ? NC-1 : cy+1;
    int x0 = cx-1 < 0 ? 0 : cx-1, x1 = cx+1 > NC-1 ? NC-1 : cx+1;
    for (int gz = z0; gz <= z1; ++gz)
      for (int gy = y0; gy <= y1; ++gy)
        scan_row(gz, gy, x0, x1);
  }

  int R = 1;
  while (true) {
    // distance from x to nearest UNexamined cell (inf where clamped at domain)
    float b = BIGF;
    if (cx - R >= 0)    b = fminf(b, xpx - (float)(cx-R)*CELLW);
    if (cx + R <= NC-2) b = fminf(b, (float)(cx+R+1)*CELLW - xpx);
    if (cy - R >= 0)    b = fminf(b, xpy - (float)(cy-R)*CELLW);
    if (cy + R <= NC-2) b = fminf(b, (float)(cy+R+1)*CELLW - xpy);
    if (cz - R >= 0)    b = fminf(b, xpz - (float)(cz-R)*CELLW);
    if (cz + R <= NC-2) b = fminf(b, (float)(cz+R+1)*CELLW - xpz);
    b = fmaxf(b - 1e-4f, 0.0f);   // conservative vs binning rounding
    if (s[15] <= b*b || R >= NC) break;
    ++R;
    int z0 = cz-R < 0 ? 0 : cz-R, z1 = cz+R > NC-1 ? NC-1 : cz+R;
    int y0 = cy-R < 0 ? 0 : cy-R, y1 = cy+R > NC-1 ? NC-1 : cy+R;
    int x0 = cx-R < 0 ? 0 : cx-R, x1 = cx+R > NC-1 ? NC-1 : cx+R;
    for (int gz = z0; gz <= z1; ++gz) {
      int dzz = gz - cz; if (dzz < 0) dzz = -dzz;
      for (int gy = y0; gy <= y1; ++gy) {
        int dyy = gy - cy; if (dyy < 0) dyy = -dyy;
        if (dzz == R || dyy == R) {
          scan_row(gz, gy, x0, x1);
        } else {
          if (cx - R >= 0)    scan_row(gz, gy, cx-R, cx-R);
          if (cx + R <= NC-1) scan_row(gz, gy, cx+R, cx+R);
        }
      }
    }
  }

  // coalesced pair writes: [j][gid]
  #pragma unroll
  for (int j = 0; j < 16; ++j) {
    pd[j*N_PTS + gid] = s[j];
    pi[j*N_PTS + gid] = (unsigned short)si[j];
  }
}

// ---- split path kernel B: MLP only ----
__global__ void __launch_bounds__(256) mlp_kernel(
    const float* __restrict__ yat,
    const float* __restrict__ W1, const float* __restrict__ b1,
    const float* __restrict__ W2, const float* __restrict__ b2,
    const float* __restrict__ W3, const float* __restrict__ b3,
    const float* __restrict__ g1, const float* __restrict__ be1,
    const float* __restrict__ m1, const float* __restrict__ v1,
    const float* __restrict__ g2, const float* __restrict__ be2,
    const float* __restrict__ m2, const float* __restrict__ v2,
    const float* __restrict__ pd, const unsigned short* __restrict__ pi,
    const int* __restrict__ xorder, float* __restrict__ out)
{
  __shared__ float wlds[1200];
  int t = threadIdx.x;
  stage_weights(wlds, t, W1,b1,W2,b2,W3,b3, g1,be1,m1,v1, g2,be2,m2,v2);
  __syncthreads();

  int gid = blockIdx.x * 256 + t;
  int p = xorder[gid];

  const float* W1t = wlds;
  const float* W2t = wlds + 320;
  const float* W3t = wlds + 576;
  const float* sb1 = wlds + 1088;
  const float* sb2 = wlds + 1104;
  const float* sb3 = wlds + 1120;
  const float* S1 = wlds + 1136;
  const float* T1 = wlds + 1152;
  const float* S2 = wlds + 1168;
  const float* T2 = wlds + 1184;

  float fx1[16], fx2[16];
  #pragma unroll
  for (int o = 0; o < 16; ++o) { fx1[o] = 0.0f; fx2[o] = 0.0f; }

  #pragma unroll 1
  for (int j = 0; j < 16; ++j) {
    float dist = pd[j*N_PTS + gid];           // coalesced
    int id = (int)pi[j*N_PTS + gid];          // coalesced
    float invd = 1.0f / dist;                 // feature = 1/(squared dist)
    const float4* a4 = (const float4*)(yat + ((size_t)id << 4));
    float4 q0 = a4[0], q1 = a4[1], q2 = a4[2], q3 = a4[3];
    float a[16];
    a[0]=q0.x; a[1]=q0.y; a[2]=q0.z; a[3]=q0.w;
    a[4]=q1.x; a[5]=q1.y; a[6]=q1.z; a[7]=q1.w;
    a[8]=q2.x; a[9]=q2.y; a[10]=q2.z; a[11]=q2.w;
    a[12]=q3.x; a[13]=q3.y; a[14]=q3.z; a[15]=q3.w;
    float h[16];
    #pragma unroll
    for (int o = 0; o < 16; ++o) {
      float acc = fmaf(invd, W1t[o*20 + 16], sb1[o]);
      #pragma unroll
      for (int i = 0; i < 16; ++i) acc = fmaf(a[i], W1t[o*20 + i], acc);
      acc = fmaxf(acc, 0.2f * acc);           // leaky_relu(0.2)
      float hv = fmaf(acc, S1[o], T1[o]);     // folded BN1
      h[o] = hv;
      fx1[o] += hv;
    }
    #pragma unroll
    for (int o = 0; o < 16; ++o) {
      float acc = sb2[o];
      #pragma unroll
      for (int i = 0; i < 16; ++i) acc = fmaf(h[i], W2t[o*16 + i], acc);
      acc = fmaxf(acc, 0.2f * acc);
      fx2[o] += fmaf(acc, S2[o], T2[o]);      // folded BN2
    }
  }

  float res[16];
  #pragma unroll
  for (int o = 0; o < 16; ++o) {
    float acc = sb3[o];
    #pragma unroll
    for (int i = 0; i < 16; ++i) acc = fmaf(fx1[i], W3t[o*32 + i], acc);
    #pragma unroll
    for (int i = 0; i < 16; ++i) acc = fmaf(fx2[i], W3t[o*32 + 16 + i], acc);
    res[o] = acc;
  }
  float* op = out + ((size_t)p << 4);
  float4 r;
  r.x=res[0]; r.y=res[1]; r.z=res[2]; r.w=res[3];   ((float4*)op)[0] = r;
  r.x=res[4]; r.y=res[5]; r.z=res[6]; r.w=res[7];   ((float4*)op)[1] = r;
  r.x=res[8]; r.y=res[9]; r.z=res[10]; r.w=res[11]; ((float4*)op)[2] = r;
  r.x=res[12]; r.y=res[13]; r.z=res[14]; r.w=res[15];((float4*)op)[3] = r;
}

// ---- fallback 1: round-1 fused kernel (used only if ws too small for split) ----
__device__ __forceinline__ void mlp_and_store(const float* lds, const float2* spill, int t,
    const float* __restrict__ yat, float* __restrict__ out, int p)
{
  const float* W1t = lds;
  const float* W2t = lds + 320;
  const float* W3t = lds + 576;
  const float* sb1 = lds + 1088;
  const float* sb2 = lds + 1104;
  const float* sb3 = lds + 1120;
  const float* S1 = lds + 1136;
  const float* T1 = lds + 1152;
  const float* S2 = lds + 1168;
  const float* T2 = lds + 1184;

  float fx1[16], fx2[16];
  #pragma unroll
  for (int o = 0; o < 16; ++o) { fx1[o] = 0.0f; fx2[o] = 0.0f; }

  #pragma unroll 1
  for (int j = 0; j < 16; ++j) {
    float2 sv = spill[j*256 + t];
    float invd = 1.0f / sv.x;
    int id = __float_as_int(sv.y);
    const float4* a4 = (const float4*)(yat + ((size_t)id << 4));
    float4 q0 = a4[0], q1 = a4[1], q2 = a4[2], q3 = a4[3];
    float a[16];
    a[0]=q0.x; a[1]=q0.y; a[2]=q0.z; a[3]=q0.w;
    a[4]=q1.x; a[5]=q1.y; a[6]=q1.z; a[7]=q1.w;
    a[8]=q2.x; a[9]=q2.y; a[10]=q2.z; a[11]=q2.w;
    a[12]=q3.x; a[13]=q3.y; a[14]=q3.z; a[15]=q3.w;
    float h[16];
    #pragma unroll
    for (int o = 0; o < 16; ++o) {
      float acc = fmaf(invd, W1t[o*20 + 16], sb1[o]);
      #pragma unroll
      for (int i = 0; i < 16; ++i) acc = fmaf(a[i], W1t[o*20 + i], acc);
      acc = fmaxf(acc, 0.2f * acc);
      float hv = fmaf(acc, S1[o], T1[o]);
      h[o] = hv;
      fx1[o] += hv;
    }
    #pragma unroll
    for (int o = 0; o < 16; ++o) {
      float acc = sb2[o];
      #pragma unroll
      for (int i = 0; i < 16; ++i) acc = fmaf(h[i], W2t[o*16 + i], acc);
      acc = fmaxf(acc, 0.2f * acc);
      fx2[o] += fmaf(acc, S2[o], T2[o]);
    }
  }

  float res[16];
  #pragma unroll
  for (int o = 0; o < 16; ++o) {
    float acc = sb3[o];
    #pragma unroll
    for (int i = 0; i < 16; ++i) acc = fmaf(fx1[i], W3t[o*32 + i], acc);
    #pragma unroll
    for (int i = 0; i < 16; ++i) acc = fmaf(fx2[i], W3t[o*32 + 16 + i], acc);
    res[o] = acc;
  }
  float* op = out + ((size_t)p << 4);
  float4 r;
  r.x=res[0]; r.y=res[1]; r.z=res[2]; r.w=res[3];   ((float4*)op)[0] = r;
  r.x=res[4]; r.y=res[5]; r.z=res[6]; r.w=res[7];   ((float4*)op)[1] = r;
  r.x=res[8]; r.y=res[9]; r.z=res[10]; r.w=res[11]; ((float4*)op)[2] = r;
  r.x=res[12]; r.y=res[13]; r.z=res[14]; r.w=res[15];((float4*)op)[3] = r;
}

__global__ void __launch_bounds__(256) knn_mlp_fused_kernel(
    const float* __restrict__ x, const float* __restrict__ yat,
    const float* __restrict__ W1, const float* __restrict__ b1,
    const float* __restrict__ W2, const float* __restrict__ b2,
    const float* __restrict__ W3, const float* __restrict__ b3,
    const float* __restrict__ g1, const float* __restrict__ be1,
    const float* __restrict__ m1, const float* __restrict__ v1,
    const float* __restrict__ g2, const float* __restrict__ be2,
    const float* __restrict__ m2, const float* __restrict__ v2,
    const float4* __restrict__ ys4, const int* __restrict__ ystart,
    const int* __restrict__ xorder, float* __restrict__ out)
{
  __shared__ float lds[1200];
  __shared__ float2 spill[4096];
  int t = threadIdx.x;
  stage_weights(lds, t, W1,b1,W2,b2,W3,b3, g1,be1,m1,v1, g2,be2,m2,v2);
  __syncthreads();

  int gid = blockIdx.x * 256 + t;
  int p = xorder[gid];
  float xpx = x[3*p], xpy = x[3*p+1], xpz = x[3*p+2];
  int cx = cell_coord(xpx), cy = cell_coord(xpy), cz = cell_coord(xpz);

  float s[16]; int si[16];
  #pragma unroll
  for (int j = 0; j < 16; ++j) { s[j] = BIGF; si[j] = 0; }

  auto scan_row = [&](int gz, int gy, int xa, int xb) {
    int rowbase = (gz*NC + gy)*NC;
    int r0 = ystart[rowbase + xa];
    int r1 = ystart[rowbase + xb + 1];
    for (int i = r0; i < r1; ++i) {
      float4 q = ys4[i];
      float dx = xpx - q.x, dy = xpy - q.y, dz = xpz - q.z;
      float d = fmaf(dx, dx, fmaf(dy, dy, dz*dz));
      if (d < s[15]) topk_insert(s, si, d, __float_as_int(q.w));
    }
  };

  {
    int z0 = cz-1 < 0 ? 0 : cz-1, z1 = cz+1 > NC-1 ? NC-1 : cz+1;
    int y0 = cy-1 < 0 ? 0 : cy-1, y1 = cy+1 > NC-1 ? NC-1 : cy+1;
    int x0 = cx-1 < 0 ? 0 : cx-1, x1 = cx+1 > NC-1 ? NC-1 : cx+1;
    for (int gz = z0; gz <= z1; ++gz)
      for (int gy = y0; gy <= y1; ++gy)
        scan_row(gz, gy, x0, x1);
  }

  int R = 1;
  while (true) {
    float b = BIGF;
    if (cx - R >= 0)    b = fminf(b, xpx - (float)(cx-R)*CELLW);
    if (cx + R <= NC-2) b = fminf(b, (float)(cx+R+1)*CELLW - xpx);
    if (cy - R >= 0)    b = fminf(b, xpy - (float)(cy-R)*CELLW);
    if (cy + R <= NC-2) b = fminf(b, (float)(cy+R+1)*CELLW - xpy);
    if (cz - R >= 0)    b = fminf(b, xpz - (float)(cz-R)*CELLW);
    if (cz + R <= NC-2) b = fminf(b, (float)(cz+R+1)*CELLW - xpz);
    b = fmaxf(b - 1e-4f, 0.0f);
    if (s[15] <= b*b || R >= NC) break;
    ++R;
    int z0 = cz-R < 0 ? 0 : cz-R, z1 = cz+R > NC-1 ? NC-1 : cz+R;
    int y0 = cy-R < 0 ? 0 : cy-R, y1 = cy+R > NC-1 ? NC-1 : cy+R;
    int x0 = cx-R < 0 ? 0 : cx-R, x1 = cx+R > NC-1 ? NC-1 : cx+R;
    for (int gz = z0; gz <= z1; ++gz) {
      int dzz = gz - cz; if (dzz < 0) dzz = -dzz;
      for (int gy = y0; gy <= y1; ++gy) {
        int dyy = gy - cy; if (dyy < 0) dyy = -dyy;
        if (dzz == R || dyy == R) {
          scan_row(gz, gy, x0, x1);
        } else {
          if (cx - R >= 0)    scan_row(gz, gy, cx-R, cx-R);
          if (cx + R <= NC-1) scan_row(gz, gy, cx+R, cx+R);
        }
      }
    }
  }

  #pragma unroll
  for (int j = 0; j < 16; ++j) spill[j*256 + t] = make_float2(s[j], __int_as_float(si[j]));
  mlp_and_store(lds, spill, t, yat, out, p);
}

// ---- fallback 2: brute force (no workspace needed) ----
__global__ void __launch_bounds__(256) brute_kernel(
    const float* __restrict__ x, const float* __restrict__ y, const float* __restrict__ yat,
    const float* __restrict__ W1, const float* __restrict__ b1,
    const float* __restrict__ W2, const float* __restrict__ b2,
    const float* __restrict__ W3, const float* __restrict__ b3,
    const float* __restrict__ g1, const float* __restrict__ be1,
    const float* __restrict__ m1, const float* __restrict__ v1,
    const float* __restrict__ g2, const float* __restrict__ be2,
    const float* __restrict__ m2, const float* __restrict__ v2,
    float* __restrict__ out)
{
  __shared__ float lds[1200];
  __shared__ float2 spill[4096];
  __shared__ float4 ybuf[1024];
  int t = threadIdx.x;
  stage_weights(lds, t, W1,b1,W2,b2,W3,b3, g1,be1,m1,v1, g2,be2,m2,v2);

  int gid = blockIdx.x * 256 + t;
  float xpx = x[3*gid], xpy = x[3*gid+1], xpz = x[3*gid+2];
  float s[16]; int si[16];
  #pragma unroll
  for (int j = 0; j < 16; ++j) { s[j] = BIGF; si[j] = 0; }

  for (int base = 0; base < M_PTS; base += 1024) {
    int nload = M_PTS - base; if (nload > 1024) nload = 1024;
    __syncthreads();
    for (int k = t; k < nload; k += 256) {
      int i = base + k;
      ybuf[k] = make_float4(y[3*i], y[3*i+1], y[3*i+2], __int_as_float(i));
    }
    __syncthreads();
    for (int i2 = 0; i2 < nload; ++i2) {
      float4 q = ybuf[i2];
      float dx = xpx - q.x, dy = xpy - q.y, dz = xpz - q.z;
      float d = fmaf(dx, dx, fmaf(dy, dy, dz*dz));
      if (d < s[15]) topk_insert(s, si, d, __float_as_int(q.w));
    }
  }

  #pragma unroll
  for (int j = 0; j < 16; ++j) spill[j*256 + t] = make_float2(s[j], __int_as_float(si[j]));
  mlp_and_store(lds, spill, t, yat, out, gid);
}

extern "C" void kernel_launch(void* const* d_in, const int* in_sizes, int n_in,
                              void* d_out, int out_size, void* d_ws, size_t ws_size,
                              hipStream_t stream) {
  const float* x   = (const float*)d_in[0];
  const float* y   = (const float*)d_in[1];
  const float* yat = (const float*)d_in[2];
  const float* W1  = (const float*)d_in[5];
  const float* b1  = (const float*)d_in[6];
  const float* W2  = (const float*)d_in[7];
  const float* b2  = (const float*)d_in[8];
  const float* W3  = (const float*)d_in[9];
  const float* b3  = (const float*)d_in[10];
  const float* g1  = (const float*)d_in[11];
  const float* be1 = (const float*)d_in[12];
  const float* m1  = (const float*)d_in[13];
  const float* v1  = (const float*)d_in[14];
  const float* g2  = (const float*)d_in[15];
  const float* be2 = (const float*)d_in[16];
  const float* m2  = (const float*)d_in[17];
  const float* v2  = (const float*)d_in[18];
  float* out = (float*)d_out;

  // split-path ws layout (bytes):
  //   ys4    @ 0        : 320000
  //   xorder @ 320000   : 327680
  //   pd     @ 647680   : 5242880   (16 * N * 4)
  //   pi     @ 5890560  : 2621440   (16 * N * 2)
  //   ycnt   @ 8512000  : 8800
  //   xcnt   @ 8520800  : 8800
  //   ystart @ 8529600  : 8800
  //   ycur   @ 8538400  : 8800
  //   xstart @ 8547200  : 8800
  //   xcur   @ 8556000  : 8800      -> end 8564800
  const size_t WS_SPLIT = 8564800;
  const size_t WS_FUSED = 700480;

  if (ws_size >= WS_SPLIT) {
    char* ws = (char*)d_ws;
    float4* ys4 = (float4*)(ws);
    int* xorder = (int*)(ws + 320000);
    float* pd   = (float*)(ws + 647680);
    unsigned short* pi = (unsigned short*)(ws + 5890560);
    int* ycnt   = (int*)(ws + 8512000);
    int* xcnt   = (int*)(ws + 8520800);
    int* ystart = (int*)(ws + 8529600);
    int* ycur   = (int*)(ws + 8538400);
    int* xstart = (int*)(ws + 8547200);
    int* xcur   = (int*)(ws + 8556000);

    hipMemsetAsync(ws + 8512000, 0, 17600, stream);   // ycnt + xcnt
    int grid_mn = (M_PTS + N_PTS + 255) / 256;
    hist_both_kernel<<<grid_mn, 256, 0, stream>>>(y, x, ycnt, xcnt);
    scan2_kernel<<<2, 1024, 0, stream>>>(ycnt, ystart, ycur, xcnt, xstart, xcur);
    scatter_both_kernel<<<grid_mn, 256, 0, stream>>>(y, x, ycur, xcur, ys4, xorder);
    sortcell_kernel<<<(NCELLS+255)/256, 256, 0, stream>>>(ys4, ystart);
    knn_kernel<<<N_PTS/256, 256, 0, stream>>>(x, ys4, ystart, xorder, pd, pi);
    mlp_kernel<<<N_PTS/256, 256, 0, stream>>>(yat, W1,b1,W2,b2,W3,b3,
        g1,be1,m1,v1, g2,be2,m2,v2, pd, pi, xorder, out);
  } else if (ws_size >= WS_FUSED) {
    char* ws = (char*)d_ws;
    float4* ys4 = (float4*)(ws);
    int* xorder = (int*)(ws + 320000);
    int* ycnt   = (int*)(ws + 647680);
    int* xcnt   = (int*)(ws + 656480);
    int* ystart = (int*)(ws + 665280);
    int* ycur   = (int*)(ws + 674080);
    int* xstart = (int*)(ws + 682880);
    int* xcur   = (int*)(ws + 691680);

    hipMemsetAsync(ws + 647680, 0, 17588, stream);
    int grid_mn = (M_PTS + N_PTS + 255) / 256;
    hist_both_kernel<<<grid_mn, 256, 0, stream>>>(y, x, ycnt, xcnt);
    scan2_kernel<<<2, 1024, 0, stream>>>(ycnt, ystart, ycur, xcnt, xstart, xcur);
    scatter_both_kernel<<<grid_mn, 256, 0, stream>>>(y, x, ycur, xcur, ys4, xorder);
    sortcell_kernel<<<(NCELLS+255)/256, 256, 0, stream>>>(ys4, ystart);
    knn_mlp_fused_kernel<<<N_PTS/256, 256, 0, stream>>>(x, yat, W1,b1,W2,b2,W3,b3,
        g1,be1,m1,v1, g2,be2,m2,v2, ys4, ystart, xorder, out);
  } else {
    brute_kernel<<<N_PTS/256, 256, 0, stream>>>(x, y, yat, W1,b1,W2,b2,W3,b3,
        g1,be1,m1,v1, g2,be2,m2,v2, out);
  }
}

// Round 4
// 237.328 us; speedup vs baseline: 5.2613x; 2.1674x over previous
//
#include <hip/hip_runtime.h>

#define N_PTS 81920
#define M_PTS 20000
#define NC 13
#define NCELLS 2197
#define CELLW 0.7692307692f
#define INVCELL 1.3f
#define BIGF 3.0e38f

__device__ __forceinline__ int clampi(int v, int lo, int hi) {
  return v < lo ? lo : (v > hi ? hi : v);
}
__device__ __forceinline__ int cell_coord(float p) {
  return clampi((int)(p * INVCELL), 0, NC - 1);
}

// ---- setup kernels ----

__global__ void hist_both_kernel(const float* __restrict__ y, const float* __restrict__ x,
                                 int* __restrict__ ycnt, int* __restrict__ xcnt) {
  int i = blockIdx.x * blockDim.x + threadIdx.x;
  if (i < M_PTS) {
    int c = (cell_coord(y[3*i+2])*NC + cell_coord(y[3*i+1]))*NC + cell_coord(y[3*i]);
    atomicAdd(&ycnt[c], 1);
  } else {
    int j = i - M_PTS;
    if (j < N_PTS) {
      int c = (cell_coord(x[3*j+2])*NC + cell_coord(x[3*j+1]))*NC + cell_coord(x[3*j]);
      atomicAdd(&xcnt[c], 1);
    }
  }
}

__global__ void scan2_kernel(const int* __restrict__ ycnt, int* __restrict__ ystart, int* __restrict__ ycur,
                             const int* __restrict__ xcnt, int* __restrict__ xstart, int* __restrict__ xcur) {
  const int* cnt = (blockIdx.x == 0) ? ycnt : xcnt;
  int* start     = (blockIdx.x == 0) ? ystart : xstart;
  int* cursor    = (blockIdx.x == 0) ? ycur : xcur;
  __shared__ int tmp[1024];
  int tid = threadIdx.x;
  int chunk = (NCELLS + 1023) >> 10;
  int base = tid * chunk;
  int sum = 0;
  for (int k = 0; k < chunk; ++k) {
    int j = base + k;
    if (j < NCELLS) sum += cnt[j];
  }
  tmp[tid] = sum;
  __syncthreads();
  for (int off = 1; off < 1024; off <<= 1) {
    int v = (tid >= off) ? tmp[tid - off] : 0;
    __syncthreads();
    tmp[tid] += v;
    __syncthreads();
  }
  int run = tmp[tid] - sum;
  for (int k = 0; k < chunk; ++k) {
    int j = base + k;
    if (j < NCELLS) { start[j] = run; cursor[j] = run; run += cnt[j]; }
  }
  if (tid == 1023) start[NCELLS] = tmp[1023];
}

__global__ void scatter_both_kernel(const float* __restrict__ y, const float* __restrict__ x,
                                    int* __restrict__ ycur, int* __restrict__ xcur,
                                    float4* __restrict__ ys4, int* __restrict__ xorder) {
  int i = blockIdx.x * blockDim.x + threadIdx.x;
  if (i < M_PTS) {
    float px = y[3*i], py = y[3*i+1], pz = y[3*i+2];
    int c = (cell_coord(pz)*NC + cell_coord(py))*NC + cell_coord(px);
    int pos = atomicAdd(&ycur[c], 1);
    ys4[pos] = make_float4(px, py, pz, __int_as_float(i));
  } else {
    int j = i - M_PTS;
    if (j < N_PTS) {
      int c = (cell_coord(x[3*j+2])*NC + cell_coord(x[3*j+1]))*NC + cell_coord(x[3*j]);
      int pos = atomicAdd(&xcur[c], 1);
      xorder[pos] = j;
    }
  }
}

// determinism: in-cell sort by original index (atomic scatter order varies per run)
__global__ void sortcell_kernel(float4* __restrict__ ys4, const int* __restrict__ ystart) {
  int c = blockIdx.x * blockDim.x + threadIdx.x;
  if (c >= NCELLS) return;
  int r0 = ystart[c], r1 = ystart[c+1];
  for (int i = r0 + 1; i < r1; ++i) {
    float4 v = ys4[i];
    int key = __float_as_int(v.w);
    int j = i - 1;
    while (j >= r0 && __float_as_int(ys4[j].w) > key) { ys4[j+1] = ys4[j]; --j; }
    ys4[j+1] = v;
  }
}

// ---- shared helpers ----

// sorted top-16 insert, fully unrolled (static register indices only);
// caller guarantees d < s[15]
__device__ __forceinline__ void topk_insert(float (&s)[16], int (&si)[16], float d, int qi) {
  #pragma unroll
  for (int j = 15; j >= 1; --j) {
    bool c1 = d < s[j-1];
    bool c2 = d < s[j];
    float ns = c1 ? s[j-1] : (c2 ? d : s[j]);
    int  ni = c1 ? si[j-1] : (c2 ? qi : si[j]);
    s[j] = ns; si[j] = ni;
  }
  if (d < s[0]) { si[0] = qi; s[0] = d; }
}

// ---- split path kernel A: kNN only (low register pressure, no spills) ----
__global__ void __launch_bounds__(256) knn_kernel(
    const float* __restrict__ x,
    const float4* __restrict__ ys4, const int* __restrict__ ystart,
    const int* __restrict__ xorder,
    float* __restrict__ pd, unsigned short* __restrict__ pi)
{
  int gid = blockIdx.x * 256 + threadIdx.x;   // grid exactly N_PTS/256
  int p = xorder[gid];
  float xpx = x[3*p], xpy = x[3*p+1], xpz = x[3*p+2];
  int cx = cell_coord(xpx), cy = cell_coord(xpy), cz = cell_coord(xpz);

  float s[16]; int si[16];
  #pragma unroll
  for (int j = 0; j < 16; ++j) { s[j] = BIGF; si[j] = 0; }

  auto scan_row = [&](int gz, int gy, int xa, int xb) {
    int rowbase = (gz*NC + gy)*NC;
    int r0 = ystart[rowbase + xa];
    int r1 = ystart[rowbase + xb + 1];
    int i = r0;
    for (; i + 2 <= r1; i += 2) {
      float4 q0 = ys4[i];
      float4 q1 = ys4[i+1];
      float dx0 = xpx - q0.x, dy0 = xpy - q0.y, dz0 = xpz - q0.z;
      float dx1 = xpx - q1.x, dy1 = xpy - q1.y, dz1 = xpz - q1.z;
      float d0 = fmaf(dx0, dx0, fmaf(dy0, dy0, dz0*dz0));
      float d1 = fmaf(dx1, dx1, fmaf(dy1, dy1, dz1*dz1));
      if (d0 < s[15]) topk_insert(s, si, d0, __float_as_int(q0.w));
      if (d1 < s[15]) topk_insert(s, si, d1, __float_as_int(q1.w));
    }
    if (i < r1) {
      float4 q = ys4[i];
      float dx = xpx - q.x, dy = xpy - q.y, dz = xpz - q.z;
      float d = fmaf(dx, dx, fmaf(dy, dy, dz*dz));
      if (d < s[15]) topk_insert(s, si, d, __float_as_int(q.w));
    }
  };

  { // initial 3x3x3 (clamped); contiguous x-cells scanned as one range
    int z0 = cz-1 < 0 ? 0 : cz-1, z1 = cz+1 > NC-1 ? NC-1 : cz+1;
    int y0 = cy-1 < 0 ? 0 : cy-1, y1 = cy+1 > NC-1 ? NC-1 : cy+1;
    int x0 = cx-1 < 0 ? 0 : cx-1, x1 = cx+1 > NC-1 ? NC-1 : cx+1;
    for (int gz = z0; gz <= z1; ++gz)
      for (int gy = y0; gy <= y1; ++gy)
        scan_row(gz, gy, x0, x1);
  }

  int R = 1;
  while (true) {
    // distance from x to nearest UNexamined cell (inf where clamped at domain)
    float b = BIGF;
    if (cx - R >= 0)    b = fminf(b, xpx - (float)(cx-R)*CELLW);
    if (cx + R <= NC-2) b = fminf(b, (float)(cx+R+1)*CELLW - xpx);
    if (cy - R >= 0)    b = fminf(b, xpy - (float)(cy-R)*CELLW);
    if (cy + R <= NC-2) b = fminf(b, (float)(cy+R+1)*CELLW - xpy);
    if (cz - R >= 0)    b = fminf(b, xpz - (float)(cz-R)*CELLW);
    if (cz + R <= NC-2) b = fminf(b, (float)(cz+R+1)*CELLW - xpz);
    b = fmaxf(b - 1e-4f, 0.0f);   // conservative vs binning rounding
    if (s[15] <= b*b || R >= NC) break;
    ++R;
    int z0 = cz-R < 0 ? 0 : cz-R, z1 = cz+R > NC-1 ? NC-1 : cz+R;
    int y0 = cy-R < 0 ? 0 : cy-R, y1 = cy+R > NC-1 ? NC-1 : cy+R;
    int x0 = cx-R < 0 ? 0 : cx-R, x1 = cx+R > NC-1 ? NC-1 : cx+R;
    for (int gz = z0; gz <= z1; ++gz) {
      int dzz = gz - cz; if (dzz < 0) dzz = -dzz;
      for (int gy = y0; gy <= y1; ++gy) {
        int dyy = gy - cy; if (dyy < 0) dyy = -dyy;
        if (dzz == R || dyy == R) {
          scan_row(gz, gy, x0, x1);
        } else {
          if (cx - R >= 0)    scan_row(gz, gy, cx-R, cx-R);
          if (cx + R <= NC-1) scan_row(gz, gy, cx+R, cx+R);
        }
      }
    }
  }

  // [gid][j] layout: each thread writes 64B + 32B contiguous; the MLP kernel's
  // 16-lane groups then read 64B/128B lines coalesced.
  #pragma unroll
  for (int j = 0; j < 16; ++j) {
    pd[gid*16 + j] = s[j];
    pi[gid*16 + j] = (unsigned short)si[j];
  }
}

// ---- split path kernel B: MLP, one lane per (point, neighbor) ----
// 16-lane group = one point. No loops over neighbors -> nothing to hoist/spill.
// Weights read from global with wave-uniform compile-time offsets (s_load path).
// Cross-lane sums via DPP row_ror (VALU pipe, row==16 lanes == our group).

template<int CTRL>
__device__ __forceinline__ float ror_add(float v) {
  int r = __builtin_amdgcn_update_dpp(0, __float_as_int(v), CTRL, 0xF, 0xF, true);
  return v + __int_as_float(r);
}
__device__ __forceinline__ float red16(float v) {
  v = ror_add<0x121>(v);   // row_ror:1
  v = ror_add<0x122>(v);   // row_ror:2
  v = ror_add<0x124>(v);   // row_ror:4
  v = ror_add<0x128>(v);   // row_ror:8
  return v;                // every lane in the 16-row holds the 16-lane sum
}

__global__ void __launch_bounds__(256) mlp_kernel(
    const float* __restrict__ yat,
    const float* __restrict__ W1, const float* __restrict__ b1,
    const float* __restrict__ W2, const float* __restrict__ b2,
    const float* __restrict__ W3, const float* __restrict__ b3,
    const float* __restrict__ g1, const float* __restrict__ be1,
    const float* __restrict__ m1, const float* __restrict__ v1,
    const float* __restrict__ g2, const float* __restrict__ be2,
    const float* __restrict__ m2, const float* __restrict__ v2,
    const float* __restrict__ pd, const unsigned short* __restrict__ pi,
    const int* __restrict__ xorder, float* __restrict__ out)
{
  int t = threadIdx.x;
  int o = t & 15;                              // lane's neighbor slot / out channel
  int gid = (blockIdx.x * 256 + t) >> 4;       // grid = N_PTS*16 threads
  int p = xorder[gid];

  float dist = pd[gid*16 + o];                 // 64B per group, coalesced
  int id = (int)pi[gid*16 + o];
  float invd = 1.0f / dist;                    // feature = 1/(squared dist)

  const float4* a4 = (const float4*)(yat + ((size_t)id << 4));
  float4 q0 = a4[0], q1 = a4[1], q2 = a4[2], q3 = a4[3];
  float a[16];
  a[0]=q0.x; a[1]=q0.y; a[2]=q0.z; a[3]=q0.w;
  a[4]=q1.x; a[5]=q1.y; a[6]=q1.z; a[7]=q1.w;
  a[8]=q2.x; a[9]=q2.y; a[10]=q2.z; a[11]=q2.w;
  a[12]=q3.x; a[13]=q3.y; a[14]=q3.z; a[15]=q3.w;

  // layer 1 (+leaky+BN1) for this lane's neighbor; all weight indices are
  // compile-time -> wave-uniform global loads (scalar path)
  float h[16];
  #pragma unroll
  for (int oo = 0; oo < 16; ++oo) {
    float acc = fmaf(invd, W1[256 + oo], b1[oo]);
    #pragma unroll
    for (int i = 0; i < 16; ++i) acc = fmaf(a[i], W1[i*16 + oo], acc);
    acc = fmaxf(acc, 0.2f * acc);              // leaky_relu(0.2)
    float S = g1[oo] * rsqrtf(v1[oo] + 1e-5f);
    h[oo] = fmaf(acc - m1[oo], S, be1[oo]);    // BN1
  }

  // layer 2 (+leaky+BN2)
  float f2[16];
  #pragma unroll
  for (int oo = 0; oo < 16; ++oo) {
    float acc = b2[oo];
    #pragma unroll
    for (int i = 0; i < 16; ++i) acc = fmaf(h[i], W2[i*16 + oo], acc);
    acc = fmaxf(acc, 0.2f * acc);
    float S = g2[oo] * rsqrtf(v2[oo] + 1e-5f);
    f2[oo] = fmaf(acc - m2[oo], S, be2[oo]);
  }

  // final layer fused with the cross-neighbor reduction:
  // fx1[i] = sum_j h_j[i] (over the 16 lanes) via DPP; this lane owns channel o.
  // W3[i*16+o]: 16 lanes read one 64B line per i -> coalesced L1 hits.
  float acc = b3[o];
  #pragma unroll
  for (int i = 0; i < 16; ++i) acc = fmaf(red16(h[i]),  W3[i*16 + o], acc);
  #pragma unroll
  for (int i = 0; i < 16; ++i) acc = fmaf(red16(f2[i]), W3[(16 + i)*16 + o], acc);

  out[(size_t)p*16 + o] = acc;                 // 64B per group, coalesced
}

// ---- fallback 1: fused kernel (only if ws too small for split path) ----
__device__ __forceinline__ void stage_weights(float* lds, int t,
    const float* W1, const float* b1, const float* W2, const float* b2,
    const float* W3, const float* b3,
    const float* g1, const float* be1, const float* m1, const float* v1,
    const float* g2, const float* be2, const float* m2, const float* v2)
{
  for (int k = t; k < 272; k += 256) { int i = k >> 4, o = k & 15; lds[o*20 + i] = W1[k]; }
  for (int k = t; k < 256; k += 256) { int i = k >> 4, o = k & 15; lds[320 + o*16 + i] = W2[k]; }
  for (int k = t; k < 512; k += 256) { int i = k >> 4, o = k & 15; lds[576 + o*32 + i] = W3[k]; }
  if (t < 16) {
    lds[1088 + t] = b1[t];
    lds[1104 + t] = b2[t];
    lds[1120 + t] = b3[t];
    float s1 = g1[t] * rsqrtf(v1[t] + 1e-5f);
    lds[1136 + t] = s1;
    lds[1152 + t] = be1[t] - m1[t]*s1;
    float s2 = g2[t] * rsqrtf(v2[t] + 1e-5f);
    lds[1168 + t] = s2;
    lds[1184 + t] = be2[t] - m2[t]*s2;
  }
}

__device__ __forceinline__ void mlp_and_store(const float* lds, const float2* spill, int t,
    const float* __restrict__ yat, float* __restrict__ out, int p)
{
  const float* W1t = lds;
  const float* W2t = lds + 320;
  const float* W3t = lds + 576;
  const float* sb1 = lds + 1088;
  const float* sb2 = lds + 1104;
  const float* sb3 = lds + 1120;
  const float* S1 = lds + 1136;
  const float* T1 = lds + 1152;
  const float* S2 = lds + 1168;
  const float* T2 = lds + 1184;

  float fx1[16], fx2[16];
  #pragma unroll
  for (int o = 0; o < 16; ++o) { fx1[o] = 0.0f; fx2[o] = 0.0f; }

  #pragma unroll 1
  for (int j = 0; j < 16; ++j) {
    float2 sv = spill[j*256 + t];
    float invd = 1.0f / sv.x;
    int id = __float_as_int(sv.y);
    const float4* a4 = (const float4*)(yat + ((size_t)id << 4));
    float4 q0 = a4[0], q1 = a4[1], q2 = a4[2], q3 = a4[3];
    float a[16];
    a[0]=q0.x; a[1]=q0.y; a[2]=q0.z; a[3]=q0.w;
    a[4]=q1.x; a[5]=q1.y; a[6]=q1.z; a[7]=q1.w;
    a[8]=q2.x; a[9]=q2.y; a[10]=q2.z; a[11]=q2.w;
    a[12]=q3.x; a[13]=q3.y; a[14]=q3.z; a[15]=q3.w;
    float h[16];
    #pragma unroll
    for (int o = 0; o < 16; ++o) {
      float acc = fmaf(invd, W1t[o*20 + 16], sb1[o]);
      #pragma unroll
      for (int i = 0; i < 16; ++i) acc = fmaf(a[i], W1t[o*20 + i], acc);
      acc = fmaxf(acc, 0.2f * acc);
      float hv = fmaf(acc, S1[o], T1[o]);
      h[o] = hv;
      fx1[o] += hv;
    }
    #pragma unroll
    for (int o = 0; o < 16; ++o) {
      float acc = sb2[o];
      #pragma unroll
      for (int i = 0; i < 16; ++i) acc = fmaf(h[i], W2t[o*16 + i], acc);
      acc = fmaxf(acc, 0.2f * acc);
      fx2[o] += fmaf(acc, S2[o], T2[o]);
    }
  }

  float res[16];
  #pragma unroll
  for (int o = 0; o < 16; ++o) {
    float acc = sb3[o];
    #pragma unroll
    for (int i = 0; i < 16; ++i) acc = fmaf(fx1[i], W3t[o*32 + i], acc);
    #pragma unroll
    for (int i = 0; i < 16; ++i) acc = fmaf(fx2[i], W3t[o*32 + 16 + i], acc);
    res[o] = acc;
  }
  float* op = out + ((size_t)p << 4);
  float4 r;
  r.x=res[0]; r.y=res[1]; r.z=res[2]; r.w=res[3];   ((float4*)op)[0] = r;
  r.x=res[4]; r.y=res[5]; r.z=res[6]; r.w=res[7];   ((float4*)op)[1] = r;
  r.x=res[8]; r.y=res[9]; r.z=res[10]; r.w=res[11]; ((float4*)op)[2] = r;
  r.x=res[12]; r.y=res[13]; r.z=res[14]; r.w=res[15];((float4*)op)[3] = r;
}

__global__ void __launch_bounds__(256) knn_mlp_fused_kernel(
    const float* __restrict__ x, const float* __restrict__ yat,
    const float* __restrict__ W1, const float* __restrict__ b1,
    const float* __restrict__ W2, const float* __restrict__ b2,
    const float* __restrict__ W3, const float* __restrict__ b3,
    const float* __restrict__ g1, const float* __restrict__ be1,
    const float* __restrict__ m1, const float* __restrict__ v1,
    const float* __restrict__ g2, const float* __restrict__ be2,
    const float* __restrict__ m2, const float* __restrict__ v2,
    const float4* __restrict__ ys4, const int* __restrict__ ystart,
    const int* __restrict__ xorder, float* __restrict__ out)
{
  __shared__ float lds[1200];
  __shared__ float2 spill[4096];
  int t = threadIdx.x;
  stage_weights(lds, t, W1,b1,W2,b2,W3,b3, g1,be1,m1,v1, g2,be2,m2,v2);
  __syncthreads();

  int gid = blockIdx.x * 256 + t;
  int p = xorder[gid];
  float xpx = x[3*p], xpy = x[3*p+1], xpz = x[3*p+2];
  int cx = cell_coord(xpx), cy = cell_coord(xpy), cz = cell_coord(xpz);

  float s[16]; int si[16];
  #pragma unroll
  for (int j = 0; j < 16; ++j) { s[j] = BIGF; si[j] = 0; }

  auto scan_row = [&](int gz, int gy, int xa, int xb) {
    int rowbase = (gz*NC + gy)*NC;
    int r0 = ystart[rowbase + xa];
    int r1 = ystart[rowbase + xb + 1];
    for (int i = r0; i < r1; ++i) {
      float4 q = ys4[i];
      float dx = xpx - q.x, dy = xpy - q.y, dz = xpz - q.z;
      float d = fmaf(dx, dx, fmaf(dy, dy, dz*dz));
      if (d < s[15]) topk_insert(s, si, d, __float_as_int(q.w));
    }
  };

  {
    int z0 = cz-1 < 0 ? 0 : cz-1, z1 = cz+1 > NC-1 ? NC-1 : cz+1;
    int y0 = cy-1 < 0 ? 0 : cy-1, y1 = cy+1 > NC-1 ? NC-1 : cy+1;
    int x0 = cx-1 < 0 ? 0 : cx-1, x1 = cx+1 > NC-1 ? NC-1 : cx+1;
    for (int gz = z0; gz <= z1; ++gz)
      for (int gy = y0; gy <= y1; ++gy)
        scan_row(gz, gy, x0, x1);
  }

  int R = 1;
  while (true) {
    float b = BIGF;
    if (cx - R >= 0)    b = fminf(b, xpx - (float)(cx-R)*CELLW);
    if (cx + R <= NC-2) b = fminf(b, (float)(cx+R+1)*CELLW - xpx);
    if (cy - R >= 0)    b = fminf(b, xpy - (float)(cy-R)*CELLW);
    if (cy + R <= NC-2) b = fminf(b, (float)(cy+R+1)*CELLW - xpy);
    if (cz - R >= 0)    b = fminf(b, xpz - (float)(cz-R)*CELLW);
    if (cz + R <= NC-2) b = fminf(b, (float)(cz+R+1)*CELLW - xpz);
    b = fmaxf(b - 1e-4f, 0.0f);
    if (s[15] <= b*b || R >= NC) break;
    ++R;
    int z0 = cz-R < 0 ? 0 : cz-R, z1 = cz+R > NC-1 ? NC-1 : cz+R;
    int y0 = cy-R < 0 ? 0 : cy-R, y1 = cy+R > NC-1 ? NC-1 : cy+R;
    int x0 = cx-R < 0 ? 0 : cx-R, x1 = cx+R > NC-1 ? NC-1 : cx+R;
    for (int gz = z0; gz <= z1; ++gz) {
      int dzz = gz - cz; if (dzz < 0) dzz = -dzz;
      for (int gy = y0; gy <= y1; ++gy) {
        int dyy = gy - cy; if (dyy < 0) dyy = -dyy;
        if (dzz == R || dyy == R) {
          scan_row(gz, gy, x0, x1);
        } else {
          if (cx - R >= 0)    scan_row(gz, gy, cx-R, cx-R);
          if (cx + R <= NC-1) scan_row(gz, gy, cx+R, cx+R);
        }
      }
    }
  }

  #pragma unroll
  for (int j = 0; j < 16; ++j) spill[j*256 + t] = make_float2(s[j], __int_as_float(si[j]));
  mlp_and_store(lds, spill, t, yat, out, p);
}

// ---- fallback 2: brute force (no workspace needed) ----
__global__ void __launch_bounds__(256) brute_kernel(
    const float* __restrict__ x, const float* __restrict__ y, const float* __restrict__ yat,
    const float* __restrict__ W1, const float* __restrict__ b1,
    const float* __restrict__ W2, const float* __restrict__ b2,
    const float* __restrict__ W3, const float* __restrict__ b3,
    const float* __restrict__ g1, const float* __restrict__ be1,
    const float* __restrict__ m1, const float* __restrict__ v1,
    const float* __restrict__ g2, const float* __restrict__ be2,
    const float* __restrict__ m2, const float* __restrict__ v2,
    float* __restrict__ out)
{
  __shared__ float lds[1200];
  __shared__ float2 spill[4096];
  __shared__ float4 ybuf[1024];
  int t = threadIdx.x;
  stage_weights(lds, t, W1,b1,W2,b2,W3,b3, g1,be1,m1,v1, g2,be2,m2,v2);

  int gid = blockIdx.x * 256 + t;
  float xpx = x[3*gid], xpy = x[3*gid+1], xpz = x[3*gid+2];
  float s[16]; int si[16];
  #pragma unroll
  for (int j = 0; j < 16; ++j) { s[j] = BIGF; si[j] = 0; }

  for (int base = 0; base < M_PTS; base += 1024) {
    int nload = M_PTS - base; if (nload > 1024) nload = 1024;
    __syncthreads();
    for (int k = t; k < nload; k += 256) {
      int i = base + k;
      ybuf[k] = make_float4(y[3*i], y[3*i+1], y[3*i+2], __int_as_float(i));
    }
    __syncthreads();
    for (int i2 = 0; i2 < nload; ++i2) {
      float4 q = ybuf[i2];
      float dx = xpx - q.x, dy = xpy - q.y, dz = xpz - q.z;
      float d = fmaf(dx, dx, fmaf(dy, dy, dz*dz));
      if (d < s[15]) topk_insert(s, si, d, __float_as_int(q.w));
    }
  }

  #pragma unroll
  for (int j = 0; j < 16; ++j) spill[j*256 + t] = make_float2(s[j], __int_as_float(si[j]));
  mlp_and_store(lds, spill, t, yat, out, gid);
}

extern "C" void kernel_launch(void* const* d_in, const int* in_sizes, int n_in,
                              void* d_out, int out_size, void* d_ws, size_t ws_size,
                              hipStream_t stream) {
  const float* x   = (const float*)d_in[0];
  const float* y   = (const float*)d_in[1];
  const float* yat = (const float*)d_in[2];
  const float* W1  = (const float*)d_in[5];
  const float* b1  = (const float*)d_in[6];
  const float* W2  = (const float*)d_in[7];
  const float* b2  = (const float*)d_in[8];
  const float* W3  = (const float*)d_in[9];
  const float* b3  = (const float*)d_in[10];
  const float* g1  = (const float*)d_in[11];
  const float* be1 = (const float*)d_in[12];
  const float* m1  = (const float*)d_in[13];
  const float* v1  = (const float*)d_in[14];
  const float* g2  = (const float*)d_in[15];
  const float* be2 = (const float*)d_in[16];
  const float* m2  = (const float*)d_in[17];
  const float* v2  = (const float*)d_in[18];
  float* out = (float*)d_out;

  // split-path ws layout (bytes):
  //   ys4    @ 0        : 320000
  //   xorder @ 320000   : 327680
  //   pd     @ 647680   : 5242880   (N * 16 * 4, [gid][j])
  //   pi     @ 5890560  : 2621440   (N * 16 * 2, [gid][j])
  //   ycnt   @ 8512000  : 8800
  //   xcnt   @ 8520800  : 8800
  //   ystart @ 8529600  : 8800
  //   ycur   @ 8538400  : 8800
  //   xstart @ 8547200  : 8800
  //   xcur   @ 8556000  : 8800      -> end 8564800
  const size_t WS_SPLIT = 8564800;
  const size_t WS_FUSED = 700480;

  if (ws_size >= WS_SPLIT) {
    char* ws = (char*)d_ws;
    float4* ys4 = (float4*)(ws);
    int* xorder = (int*)(ws + 320000);
    float* pd   = (float*)(ws + 647680);
    unsigned short* pi = (unsigned short*)(ws + 5890560);
    int* ycnt   = (int*)(ws + 8512000);
    int* xcnt   = (int*)(ws + 8520800);
    int* ystart = (int*)(ws + 8529600);
    int* ycur   = (int*)(ws + 8538400);
    int* xstart = (int*)(ws + 8547200);
    int* xcur   = (int*)(ws + 8556000);

    hipMemsetAsync(ws + 8512000, 0, 17600, stream);   // ycnt + xcnt
    int grid_mn = (M_PTS + N_PTS + 255) / 256;
    hist_both_kernel<<<grid_mn, 256, 0, stream>>>(y, x, ycnt, xcnt);
    scan2_kernel<<<2, 1024, 0, stream>>>(ycnt, ystart, ycur, xcnt, xstart, xcur);
    scatter_both_kernel<<<grid_mn, 256, 0, stream>>>(y, x, ycur, xcur, ys4, xorder);
    sortcell_kernel<<<(NCELLS+255)/256, 256, 0, stream>>>(ys4, ystart);
    knn_kernel<<<N_PTS/256, 256, 0, stream>>>(x, ys4, ystart, xorder, pd, pi);
    mlp_kernel<<<(N_PTS*16)/256, 256, 0, stream>>>(yat, W1,b1,W2,b2,W3,b3,
        g1,be1,m1,v1, g2,be2,m2,v2, pd, pi, xorder, out);
  } else if (ws_size >= WS_FUSED) {
    char* ws = (char*)d_ws;
    float4* ys4 = (float4*)(ws);
    int* xorder = (int*)(ws + 320000);
    int* ycnt   = (int*)(ws + 647680);
    int* xcnt   = (int*)(ws + 656480);
    int* ystart = (int*)(ws + 665280);
    int* ycur   = (int*)(ws + 674080);
    int* xstart = (int*)(ws + 682880);
    int* xcur   = (int*)(ws + 691680);

    hipMemsetAsync(ws + 647680, 0, 17588, stream);
    int grid_mn = (M_PTS + N_PTS + 255) / 256;
    hist_both_kernel<<<grid_mn, 256, 0, stream>>>(y, x, ycnt, xcnt);
    scan2_kernel<<<2, 1024, 0, stream>>>(ycnt, ystart, ycur, xcnt, xstart, xcur);
    scatter_both_kernel<<<grid_mn, 256, 0, stream>>>(y, x, ycur, xcur, ys4, xorder);
    sortcell_kernel<<<(NCELLS+255)/256, 256, 0, stream>>>(ys4, ystart);
    knn_mlp_fused_kernel<<<N_PTS/256, 256, 0, stream>>>(x, yat, W1,b1,W2,b2,W3,b3,
        g1,be1,m1,v1, g2,be2,m2,v2, ys4, ystart, xorder, out);
  } else {
    brute_kernel<<<N_PTS/256, 256, 0, stream>>>(x, y, yat, W1,b1,W2,b2,W3,b3,
        g1,be1,m1,v1, g2,be2,m2,v2, out);
  }
}

// Round 5
// 235.272 us; speedup vs baseline: 5.3073x; 1.0087x over previous
//
#include <hip/hip_runtime.h>

#define N_PTS 81920
#define M_PTS 20000
#define NC 13
#define NCELLS 2197
#define CELLW 0.7692307692f
#define INVCELL 1.3f
#define BIGF 3.0e38f

__device__ __forceinline__ int clampi(int v, int lo, int hi) {
  return v < lo ? lo : (v > hi ? hi : v);
}
__device__ __forceinline__ int cell_coord(float p) {
  return clampi((int)(p * INVCELL), 0, NC - 1);
}

// ---- setup kernels ----

__global__ void hist_both_kernel(const float* __restrict__ y, const float* __restrict__ x,
                                 int* __restrict__ ycnt, int* __restrict__ xcnt) {
  int i = blockIdx.x * blockDim.x + threadIdx.x;
  if (i < M_PTS) {
    int c = (cell_coord(y[3*i+2])*NC + cell_coord(y[3*i+1]))*NC + cell_coord(y[3*i]);
    atomicAdd(&ycnt[c], 1);
  } else {
    int j = i - M_PTS;
    if (j < N_PTS) {
      int c = (cell_coord(x[3*j+2])*NC + cell_coord(x[3*j+1]))*NC + cell_coord(x[3*j]);
      atomicAdd(&xcnt[c], 1);
    }
  }
}

__global__ void scan2_kernel(const int* __restrict__ ycnt, int* __restrict__ ystart, int* __restrict__ ycur,
                             const int* __restrict__ xcnt, int* __restrict__ xstart, int* __restrict__ xcur) {
  const int* cnt = (blockIdx.x == 0) ? ycnt : xcnt;
  int* start     = (blockIdx.x == 0) ? ystart : xstart;
  int* cursor    = (blockIdx.x == 0) ? ycur : xcur;
  __shared__ int tmp[1024];
  int tid = threadIdx.x;
  int chunk = (NCELLS + 1023) >> 10;
  int base = tid * chunk;
  int sum = 0;
  for (int k = 0; k < chunk; ++k) {
    int j = base + k;
    if (j < NCELLS) sum += cnt[j];
  }
  tmp[tid] = sum;
  __syncthreads();
  for (int off = 1; off < 1024; off <<= 1) {
    int v = (tid >= off) ? tmp[tid - off] : 0;
    __syncthreads();
    tmp[tid] += v;
    __syncthreads();
  }
  int run = tmp[tid] - sum;
  for (int k = 0; k < chunk; ++k) {
    int j = base + k;
    if (j < NCELLS) { start[j] = run; cursor[j] = run; run += cnt[j]; }
  }
  if (tid == 1023) start[NCELLS] = tmp[1023];
}

__global__ void scatter_both_kernel(const float* __restrict__ y, const float* __restrict__ x,
                                    int* __restrict__ ycur, int* __restrict__ xcur,
                                    float4* __restrict__ ys4, int* __restrict__ xorder) {
  int i = blockIdx.x * blockDim.x + threadIdx.x;
  if (i < M_PTS) {
    float px = y[3*i], py = y[3*i+1], pz = y[3*i+2];
    int c = (cell_coord(pz)*NC + cell_coord(py))*NC + cell_coord(px);
    int pos = atomicAdd(&ycur[c], 1);
    ys4[pos] = make_float4(px, py, pz, __int_as_float(i));
  } else {
    int j = i - M_PTS;
    if (j < N_PTS) {
      int c = (cell_coord(x[3*j+2])*NC + cell_coord(x[3*j+1]))*NC + cell_coord(x[3*j]);
      int pos = atomicAdd(&xcur[c], 1);
      xorder[pos] = j;
    }
  }
}

// (fused/brute fallback only) determinism: in-cell sort by original index
__global__ void sortcell_kernel(float4* __restrict__ ys4, const int* __restrict__ ystart) {
  int c = blockIdx.x * blockDim.x + threadIdx.x;
  if (c >= NCELLS) return;
  int r0 = ystart[c], r1 = ystart[c+1];
  for (int i = r0 + 1; i < r1; ++i) {
    float4 v = ys4[i];
    int key = __float_as_int(v.w);
    int j = i - 1;
    while (j >= r0 && __float_as_int(ys4[j].w) > key) { ys4[j+1] = ys4[j]; --j; }
    ys4[j+1] = v;
  }
}

// ---- split path kernel A: kNN with packed keys, TPP=2, 64-thread blocks ----
// key = (d_bits & 0xFFFF8000) | idx  (d>0 -> float order == bit order; idx<2^15).
// Selection is exact in key space and independent of candidate scan order
// (keys are unique), so no sortcell needed and output is replay-deterministic.
__global__ void __launch_bounds__(64) knn_kernel(
    const float* __restrict__ x,
    const float4* __restrict__ ys4, const int* __restrict__ ystart,
    const int* __restrict__ xorder,
    unsigned short* __restrict__ pi)
{
  int t = threadIdx.x;
  int sub = t & 1;                       // lane pair: 2 sub-threads per point
  int gid = blockIdx.x * 32 + (t >> 1);  // grid = 2560 blocks * 32 points
  int p = xorder[gid];
  float xpx = x[3*p], xpy = x[3*p+1], xpz = x[3*p+2];
  int cx = cell_coord(xpx), cy = cell_coord(xpy), cz = cell_coord(xpz);

  float s[16];
  #pragma unroll
  for (int j = 0; j < 16; ++j) s[j] = BIGF;

  // branchless sorted-insert of packed key: 31 VALU ops, descending update
  auto ins = [&](float k) {
    #pragma unroll
    for (int j = 15; j >= 1; --j) s[j] = fminf(fmaxf(s[j-1], k), s[j]);
    s[0] = fminf(s[0], k);
  };
  auto packkey = [&](float4 q) -> float {
    float dx = xpx - q.x, dy = xpy - q.y, dz = xpz - q.z;
    float d = fmaf(dx, dx, fmaf(dy, dy, dz*dz));
    unsigned kb = (__float_as_uint(d) & 0xFFFF8000u) | (__float_as_uint(q.w) & 0x7FFFu);
    return __uint_as_float(kb);
  };

  auto scan_row = [&](int gz, int gy, int xa, int xb) {
    int rowbase = (gz*NC + gy)*NC;
    int r0 = ystart[rowbase + xa];
    int r1 = ystart[rowbase + xb + 1];
    int i = r0 + sub;                    // stride-2 partition between subs
    for (; i + 3 <= r1; i += 4) {        // 2 candidates per iter per sub
      float4 q0 = ys4[i];
      float4 q1 = ys4[i+2];
      float k0 = packkey(q0);
      float k1 = packkey(q1);
      ins(k0);
      ins(k1);
    }
    if (i < r1) ins(packkey(ys4[i]));
  };

  { // initial 3x3x3 (clamped); contiguous x-cells scanned as one range
    int z0 = cz-1 < 0 ? 0 : cz-1, z1 = cz+1 > NC-1 ? NC-1 : cz+1;
    int y0 = cy-1 < 0 ? 0 : cy-1, y1 = cy+1 > NC-1 ? NC-1 : cy+1;
    int x0 = cx-1 < 0 ? 0 : cx-1, x1 = cx+1 > NC-1 ? NC-1 : cx+1;
    for (int gz = z0; gz <= z1; ++gz)
      for (int gy = y0; gy <= y1; ++gy)
        scan_row(gz, gy, x0, x1);
  }

  int R = 1;
  while (true) {
    // distance to nearest UNexamined cell (inf where clamped at domain)
    float b = BIGF;
    if (cx - R >= 0)    b = fminf(b, xpx - (float)(cx-R)*CELLW);
    if (cx + R <= NC-2) b = fminf(b, (float)(cx+R+1)*CELLW - xpx);
    if (cy - R >= 0)    b = fminf(b, xpy - (float)(cy-R)*CELLW);
    if (cy + R <= NC-2) b = fminf(b, (float)(cy+R+1)*CELLW - xpy);
    if (cz - R >= 0)    b = fminf(b, xpz - (float)(cz-R)*CELLW);
    if (cz + R <= NC-2) b = fminf(b, (float)(cz+R+1)*CELLW - xpz);
    b = fmaxf(b - 1e-4f, 0.0f);          // conservative vs binning rounding
    float bb = b * b;
    // min possible key in unexamined region = floor-packed b^2 (exact in key space)
    float bpack = __uint_as_float(__float_as_uint(bb) & 0xFFFF8000u);
    if (s[15] <= bpack || R >= NC) break;
    ++R;
    int z0 = cz-R < 0 ? 0 : cz-R, z1 = cz+R > NC-1 ? NC-1 : cz+R;
    int y0 = cy-R < 0 ? 0 : cy-R, y1 = cy+R > NC-1 ? NC-1 : cy+R;
    int x0 = cx-R < 0 ? 0 : cx-R, x1 = cx+R > NC-1 ? NC-1 : cx+R;
    for (int gz = z0; gz <= z1; ++gz) {
      int dzz = gz - cz; if (dzz < 0) dzz = -dzz;
      for (int gy = y0; gy <= y1; ++gy) {
        int dyy = gy - cy; if (dyy < 0) dyy = -dyy;
        if (dzz == R || dyy == R) {
          scan_row(gz, gy, x0, x1);
        } else {
          if (cx - R >= 0)    scan_row(gz, gy, cx-R, cx-R);
          if (cx + R <= NC-1) scan_row(gz, gy, cx+R, cx+R);
        }
      }
    }
  }

  // merge pair: top-16 of the union of two sorted 16-lists (bitonic lower half)
  float c[16];
  #pragma unroll
  for (int i = 0; i < 16; ++i) {
    float o = __shfl_xor(s[15 - i], 1);
    c[i] = fminf(s[i], o);
  }
  // c is a bitonic 16-sequence -> sort ascending (canonical slot order,
  // independent of partition/scan order -> deterministic output)
  #define CE(i, j) { float lo = fminf(c[i], c[j]); float hi = fmaxf(c[i], c[j]); c[i] = lo; c[j] = hi; }
  CE(0,8) CE(1,9) CE(2,10) CE(3,11) CE(4,12) CE(5,13) CE(6,14) CE(7,15)
  CE(0,4) CE(1,5) CE(2,6)  CE(3,7)  CE(8,12) CE(9,13) CE(10,14) CE(11,15)
  CE(0,2) CE(1,3) CE(4,6)  CE(5,7)  CE(8,10) CE(9,11) CE(12,14) CE(13,15)
  CE(0,1) CE(2,3) CE(4,5)  CE(6,7)  CE(8,9)  CE(10,11) CE(12,13) CE(14,15)
  #undef CE

  // each sub writes half the slots: 8 u16 indices = one 16B store
  float cv[8];
  #pragma unroll
  for (int m = 0; m < 8; ++m) cv[m] = sub ? c[8 + m] : c[m];
  unsigned w0 = (__float_as_uint(cv[0]) & 0x7FFFu) | ((__float_as_uint(cv[1]) & 0x7FFFu) << 16);
  unsigned w1 = (__float_as_uint(cv[2]) & 0x7FFFu) | ((__float_as_uint(cv[3]) & 0x7FFFu) << 16);
  unsigned w2 = (__float_as_uint(cv[4]) & 0x7FFFu) | ((__float_as_uint(cv[5]) & 0x7FFFu) << 16);
  unsigned w3 = (__float_as_uint(cv[6]) & 0x7FFFu) | ((__float_as_uint(cv[7]) & 0x7FFFu) << 16);
  uint4 W; W.x = w0; W.y = w1; W.z = w2; W.w = w3;
  ((uint4*)pi)[gid*2 + sub] = W;
}

// ---- split path kernel B: MLP, one lane per (point, neighbor) ----
template<int CTRL>
__device__ __forceinline__ float ror_add(float v) {
  int r = __builtin_amdgcn_update_dpp(0, __float_as_int(v), CTRL, 0xF, 0xF, true);
  return v + __int_as_float(r);
}
__device__ __forceinline__ float red16(float v) {
  v = ror_add<0x121>(v);   // row_ror:1
  v = ror_add<0x122>(v);   // row_ror:2
  v = ror_add<0x124>(v);   // row_ror:4
  v = ror_add<0x128>(v);   // row_ror:8
  return v;                // every lane of the 16-row holds the 16-lane sum
}

__global__ void __launch_bounds__(256) mlp_kernel(
    const float* __restrict__ yat, const float* __restrict__ x, const float* __restrict__ y,
    const float* __restrict__ W1, const float* __restrict__ b1,
    const float* __restrict__ W2, const float* __restrict__ b2,
    const float* __restrict__ W3, const float* __restrict__ b3,
    const float* __restrict__ g1, const float* __restrict__ be1,
    const float* __restrict__ m1, const float* __restrict__ v1,
    const float* __restrict__ g2, const float* __restrict__ be2,
    const float* __restrict__ m2, const float* __restrict__ v2,
    const unsigned short* __restrict__ pi,
    const int* __restrict__ xorder, float* __restrict__ out)
{
  int t = threadIdx.x;
  int o = t & 15;                              // lane's neighbor slot / out channel
  int gid = (blockIdx.x * 256 + t) >> 4;       // grid = N_PTS*16 threads
  int p = xorder[gid];

  int id = (int)pi[gid*16 + o];                // 32B per group, coalesced
  // recompute exact squared distance (selection used truncated keys)
  float xpx = x[3*p], xpy = x[3*p+1], xpz = x[3*p+2];   // broadcast within group
  float dx = xpx - y[3*id], dy = xpy - y[3*id+1], dz = xpz - y[3*id+2];
  float dist = fmaf(dx, dx, fmaf(dy, dy, dz*dz));
  float invd = 1.0f / dist;                    // feature = 1/(squared dist)

  const float4* a4 = (const float4*)(yat + ((size_t)id << 4));
  float4 q0 = a4[0], q1 = a4[1], q2 = a4[2], q3 = a4[3];
  float a[16];
  a[0]=q0.x; a[1]=q0.y; a[2]=q0.z; a[3]=q0.w;
  a[4]=q1.x; a[5]=q1.y; a[6]=q1.z; a[7]=q1.w;
  a[8]=q2.x; a[9]=q2.y; a[10]=q2.z; a[11]=q2.w;
  a[12]=q3.x; a[13]=q3.y; a[14]=q3.z; a[15]=q3.w;

  // layer 1 (+leaky+BN1); weight indices compile-time -> wave-uniform loads
  float h[16];
  #pragma unroll
  for (int oo = 0; oo < 16; ++oo) {
    float acc = fmaf(invd, W1[256 + oo], b1[oo]);
    #pragma unroll
    for (int i = 0; i < 16; ++i) acc = fmaf(a[i], W1[i*16 + oo], acc);
    acc = fmaxf(acc, 0.2f * acc);              // leaky_relu(0.2)
    float S = g1[oo] * rsqrtf(v1[oo] + 1e-5f);
    h[oo] = fmaf(acc - m1[oo], S, be1[oo]);    // BN1
  }

  // layer 2 (+leaky+BN2)
  float f2[16];
  #pragma unroll
  for (int oo = 0; oo < 16; ++oo) {
    float acc = b2[oo];
    #pragma unroll
    for (int i = 0; i < 16; ++i) acc = fmaf(h[i], W2[i*16 + oo], acc);
    acc = fmaxf(acc, 0.2f * acc);
    float S = g2[oo] * rsqrtf(v2[oo] + 1e-5f);
    f2[oo] = fmaf(acc - m2[oo], S, be2[oo]);
  }

  // final layer fused with cross-neighbor DPP reduction; lane owns channel o
  float acc = b3[o];
  #pragma unroll
  for (int i = 0; i < 16; ++i) acc = fmaf(red16(h[i]),  W3[i*16 + o], acc);
  #pragma unroll
  for (int i = 0; i < 16; ++i) acc = fmaf(red16(f2[i]), W3[(16 + i)*16 + o], acc);

  out[(size_t)p*16 + o] = acc;                 // 64B per group, coalesced
}

// ---- fallback 1: fused kernel (only if ws too small for split path) ----
__device__ __forceinline__ void stage_weights(float* lds, int t,
    const float* W1, const float* b1, const float* W2, const float* b2,
    const float* W3, const float* b3,
    const float* g1, const float* be1, const float* m1, const float* v1,
    const float* g2, const float* be2, const float* m2, const float* v2)
{
  for (int k = t; k < 272; k += 256) { int i = k >> 4, o = k & 15; lds[o*20 + i] = W1[k]; }
  for (int k = t; k < 256; k += 256) { int i = k >> 4, o = k & 15; lds[320 + o*16 + i] = W2[k]; }
  for (int k = t; k < 512; k += 256) { int i = k >> 4, o = k & 15; lds[576 + o*32 + i] = W3[k]; }
  if (t < 16) {
    lds[1088 + t] = b1[t];
    lds[1104 + t] = b2[t];
    lds[1120 + t] = b3[t];
    float s1 = g1[t] * rsqrtf(v1[t] + 1e-5f);
    lds[1136 + t] = s1;
    lds[1152 + t] = be1[t] - m1[t]*s1;
    float s2 = g2[t] * rsqrtf(v2[t] + 1e-5f);
    lds[1168 + t] = s2;
    lds[1184 + t] = be2[t] - m2[t]*s2;
  }
}

__device__ __forceinline__ void topk_insert(float (&s)[16], int (&si)[16], float d, int qi) {
  #pragma unroll
  for (int j = 15; j >= 1; --j) {
    bool c1 = d < s[j-1];
    bool c2 = d < s[j];
    float ns = c1 ? s[j-1] : (c2 ? d : s[j]);
    int  ni = c1 ? si[j-1] : (c2 ? qi : si[j]);
    s[j] = ns; si[j] = ni;
  }
  if (d < s[0]) { si[0] = qi; s[0] = d; }
}

__device__ __forceinline__ void mlp_and_store(const float* lds, const float2* spill, int t,
    const float* __restrict__ yat, float* __restrict__ out, int p)
{
  const float* W1t = lds;
  const float* W2t = lds + 320;
  const float* W3t = lds + 576;
  const float* sb1 = lds + 1088;
  const float* sb2 = lds + 1104;
  const float* sb3 = lds + 1120;
  const float* S1 = lds + 1136;
  const float* T1 = lds + 1152;
  const float* S2 = lds + 1168;
  const float* T2 = lds + 1184;

  float fx1[16], fx2[16];
  #pragma unroll
  for (int o = 0; o < 16; ++o) { fx1[o] = 0.0f; fx2[o] = 0.0f; }

  #pragma unroll 1
  for (int j = 0; j < 16; ++j) {
    float2 sv = spill[j*256 + t];
    float invd = 1.0f / sv.x;
    int id = __float_as_int(sv.y);
    const float4* a4 = (const float4*)(yat + ((size_t)id << 4));
    float4 q0 = a4[0], q1 = a4[1], q2 = a4[2], q3 = a4[3];
    float a[16];
    a[0]=q0.x; a[1]=q0.y; a[2]=q0.z; a[3]=q0.w;
    a[4]=q1.x; a[5]=q1.y; a[6]=q1.z; a[7]=q1.w;
    a[8]=q2.x; a[9]=q2.y; a[10]=q2.z; a[11]=q2.w;
    a[12]=q3.x; a[13]=q3.y; a[14]=q3.z; a[15]=q3.w;
    float h[16];
    #pragma unroll
    for (int o = 0; o < 16; ++o) {
      float acc = fmaf(invd, W1t[o*20 + 16], sb1[o]);
      #pragma unroll
      for (int i = 0; i < 16; ++i) acc = fmaf(a[i], W1t[o*20 + i], acc);
      acc = fmaxf(acc, 0.2f * acc);
      float hv = fmaf(acc, S1[o], T1[o]);
      h[o] = hv;
      fx1[o] += hv;
    }
    #pragma unroll
    for (int o = 0; o < 16; ++o) {
      float acc = sb2[o];
      #pragma unroll
      for (int i = 0; i < 16; ++i) acc = fmaf(h[i], W2t[o*16 + i], acc);
      acc = fmaxf(acc, 0.2f * acc);
      fx2[o] += fmaf(acc, S2[o], T2[o]);
    }
  }

  float res[16];
  #pragma unroll
  for (int o = 0; o < 16; ++o) {
    float acc = sb3[o];
    #pragma unroll
    for (int i = 0; i < 16; ++i) acc = fmaf(fx1[i], W3t[o*32 + i], acc);
    #pragma unroll
    for (int i = 0; i < 16; ++i) acc = fmaf(fx2[i], W3t[o*32 + 16 + i], acc);
    res[o] = acc;
  }
  float* op = out + ((size_t)p << 4);
  float4 r;
  r.x=res[0]; r.y=res[1]; r.z=res[2]; r.w=res[3];   ((float4*)op)[0] = r;
  r.x=res[4]; r.y=res[5]; r.z=res[6]; r.w=res[7];   ((float4*)op)[1] = r;
  r.x=res[8]; r.y=res[9]; r.z=res[10]; r.w=res[11]; ((float4*)op)[2] = r;
  r.x=res[12]; r.y=res[13]; r.z=res[14]; r.w=res[15];((float4*)op)[3] = r;
}

__global__ void __launch_bounds__(256) knn_mlp_fused_kernel(
    const float* __restrict__ x, const float* __restrict__ yat,
    const float* __restrict__ W1, const float* __restrict__ b1,
    const float* __restrict__ W2, const float* __restrict__ b2,
    const float* __restrict__ W3, const float* __restrict__ b3,
    const float* __restrict__ g1, const float* __restrict__ be1,
    const float* __restrict__ m1, const float* __restrict__ v1,
    const float* __restrict__ g2, const float* __restrict__ be2,
    const float* __restrict__ m2, const float* __restrict__ v2,
    const float4* __restrict__ ys4, const int* __restrict__ ystart,
    const int* __restrict__ xorder, float* __restrict__ out)
{
  __shared__ float lds[1200];
  __shared__ float2 spill[4096];
  int t = threadIdx.x;
  stage_weights(lds, t, W1,b1,W2,b2,W3,b3, g1,be1,m1,v1, g2,be2,m2,v2);
  __syncthreads();

  int gid = blockIdx.x * 256 + t;
  int p = xorder[gid];
  float xpx = x[3*p], xpy = x[3*p+1], xpz = x[3*p+2];
  int cx = cell_coord(xpx), cy = cell_coord(xpy), cz = cell_coord(xpz);

  float s[16]; int si[16];
  #pragma unroll
  for (int j = 0; j < 16; ++j) { s[j] = BIGF; si[j] = 0; }

  auto scan_row = [&](int gz, int gy, int xa, int xb) {
    int rowbase = (gz*NC + gy)*NC;
    int r0 = ystart[rowbase + xa];
    int r1 = ystart[rowbase + xb + 1];
    for (int i = r0; i < r1; ++i) {
      float4 q = ys4[i];
      float dx = xpx - q.x, dy = xpy - q.y, dz = xpz - q.z;
      float d = fmaf(dx, dx, fmaf(dy, dy, dz*dz));
      if (d < s[15]) topk_insert(s, si, d, __float_as_int(q.w));
    }
  };

  {
    int z0 = cz-1 < 0 ? 0 : cz-1, z1 = cz+1 > NC-1 ? NC-1 : cz+1;
    int y0 = cy-1 < 0 ? 0 : cy-1, y1 = cy+1 > NC-1 ? NC-1 : cy+1;
    int x0 = cx-1 < 0 ? 0 : cx-1, x1 = cx+1 > NC-1 ? NC-1 : cx+1;
    for (int gz = z0; gz <= z1; ++gz)
      for (int gy = y0; gy <= y1; ++gy)
        scan_row(gz, gy, x0, x1);
  }

  int R = 1;
  while (true) {
    float b = BIGF;
    if (cx - R >= 0)    b = fminf(b, xpx - (float)(cx-R)*CELLW);
    if (cx + R <= NC-2) b = fminf(b, (float)(cx+R+1)*CELLW - xpx);
    if (cy - R >= 0)    b = fminf(b, xpy - (float)(cy-R)*CELLW);
    if (cy + R <= NC-2) b = fminf(b, (float)(cy+R+1)*CELLW - xpy);
    if (cz - R >= 0)    b = fminf(b, xpz - (float)(cz-R)*CELLW);
    if (cz + R <= NC-2) b = fminf(b, (float)(cz+R+1)*CELLW - xpz);
    b = fmaxf(b - 1e-4f, 0.0f);
    if (s[15] <= b*b || R >= NC) break;
    ++R;
    int z0 = cz-R < 0 ? 0 : cz-R, z1 = cz+R > NC-1 ? NC-1 : cz+R;
    int y0 = cy-R < 0 ? 0 : cy-R, y1 = cy+R > NC-1 ? NC-1 : cy+R;
    int x0 = cx-R < 0 ? 0 : cx-R, x1 = cx+R > NC-1 ? NC-1 : cx+R;
    for (int gz = z0; gz <= z1; ++gz) {
      int dzz = gz - cz; if (dzz < 0) dzz = -dzz;
      for (int gy = y0; gy <= y1; ++gy) {
        int dyy = gy - cy; if (dyy < 0) dyy = -dyy;
        if (dzz == R || dyy == R) {
          scan_row(gz, gy, x0, x1);
        } else {
          if (cx - R >= 0)    scan_row(gz, gy, cx-R, cx-R);
          if (cx + R <= NC-1) scan_row(gz, gy, cx+R, cx+R);
        }
      }
    }
  }

  #pragma unroll
  for (int j = 0; j < 16; ++j) spill[j*256 + t] = make_float2(s[j], __int_as_float(si[j]));
  mlp_and_store(lds, spill, t, yat, out, p);
}

// ---- fallback 2: brute force (no workspace needed) ----
__global__ void __launch_bounds__(256) brute_kernel(
    const float* __restrict__ x, const float* __restrict__ y, const float* __restrict__ yat,
    const float* __restrict__ W1, const float* __restrict__ b1,
    const float* __restrict__ W2, const float* __restrict__ b2,
    const float* __restrict__ W3, const float* __restrict__ b3,
    const float* __restrict__ g1, const float* __restrict__ be1,
    const float* __restrict__ m1, const float* __restrict__ v1,
    const float* __restrict__ g2, const float* __restrict__ be2,
    const float* __restrict__ m2, const float* __restrict__ v2,
    float* __restrict__ out)
{
  __shared__ float lds[1200];
  __shared__ float2 spill[4096];
  __shared__ float4 ybuf[1024];
  int t = threadIdx.x;
  stage_weights(lds, t, W1,b1,W2,b2,W3,b3, g1,be1,m1,v1, g2,be2,m2,v2);

  int gid = blockIdx.x * 256 + t;
  float xpx = x[3*gid], xpy = x[3*gid+1], xpz = x[3*gid+2];
  float s[16]; int si[16];
  #pragma unroll
  for (int j = 0; j < 16; ++j) { s[j] = BIGF; si[j] = 0; }

  for (int base = 0; base < M_PTS; base += 1024) {
    int nload = M_PTS - base; if (nload > 1024) nload = 1024;
    __syncthreads();
    for (int k = t; k < nload; k += 256) {
      int i = base + k;
      ybuf[k] = make_float4(y[3*i], y[3*i+1], y[3*i+2], __int_as_float(i));
    }
    __syncthreads();
    for (int i2 = 0; i2 < nload; ++i2) {
      float4 q = ybuf[i2];
      float dx = xpx - q.x, dy = xpy - q.y, dz = xpz - q.z;
      float d = fmaf(dx, dx, fmaf(dy, dy, dz*dz));
      if (d < s[15]) topk_insert(s, si, d, __float_as_int(q.w));
    }
  }

  #pragma unroll
  for (int j = 0; j < 16; ++j) spill[j*256 + t] = make_float2(s[j], __int_as_float(si[j]));
  mlp_and_store(lds, spill, t, yat, out, gid);
}

extern "C" void kernel_launch(void* const* d_in, const int* in_sizes, int n_in,
                              void* d_out, int out_size, void* d_ws, size_t ws_size,
                              hipStream_t stream) {
  const float* x   = (const float*)d_in[0];
  const float* y   = (const float*)d_in[1];
  const float* yat = (const float*)d_in[2];
  const float* W1  = (const float*)d_in[5];
  const float* b1  = (const float*)d_in[6];
  const float* W2  = (const float*)d_in[7];
  const float* b2  = (const float*)d_in[8];
  const float* W3  = (const float*)d_in[9];
  const float* b3  = (const float*)d_in[10];
  const float* g1  = (const float*)d_in[11];
  const float* be1 = (const float*)d_in[12];
  const float* m1  = (const float*)d_in[13];
  const float* v1  = (const float*)d_in[14];
  const float* g2  = (const float*)d_in[15];
  const float* be2 = (const float*)d_in[16];
  const float* m2  = (const float*)d_in[17];
  const float* v2  = (const float*)d_in[18];
  float* out = (float*)d_out;

  // split-path ws layout (bytes):
  //   ys4    @ 0       : 320000
  //   xorder @ 320000  : 327680
  //   pi     @ 647680  : 2621440   (N*16 u16, [gid][j])
  //   ycnt   @ 3269120 : 8800
  //   xcnt   @ 3277920 : 8800
  //   ystart @ 3286720 : 8800
  //   ycur   @ 3295520 : 8800
  //   xstart @ 3304320 : 8800
  //   xcur   @ 3313120 : 8800      -> end 3321920
  const size_t WS_SPLIT = 3321920;
  const size_t WS_FUSED = 700480;

  if (ws_size >= WS_SPLIT) {
    char* ws = (char*)d_ws;
    float4* ys4 = (float4*)(ws);
    int* xorder = (int*)(ws + 320000);
    unsigned short* pi = (unsigned short*)(ws + 647680);
    int* ycnt   = (int*)(ws + 3269120);
    int* xcnt   = (int*)(ws + 3277920);
    int* ystart = (int*)(ws + 3286720);
    int* ycur   = (int*)(ws + 3295520);
    int* xstart = (int*)(ws + 3304320);
    int* xcur   = (int*)(ws + 3313120);

    hipMemsetAsync(ws + 3269120, 0, 17600, stream);   // ycnt + xcnt
    int grid_mn = (M_PTS + N_PTS + 255) / 256;
    hist_both_kernel<<<grid_mn, 256, 0, stream>>>(y, x, ycnt, xcnt);
    scan2_kernel<<<2, 1024, 0, stream>>>(ycnt, ystart, ycur, xcnt, xstart, xcur);
    scatter_both_kernel<<<grid_mn, 256, 0, stream>>>(y, x, ycur, xcur, ys4, xorder);
    // no sortcell: key-space selection is scan-order independent
    knn_kernel<<<N_PTS/32, 64, 0, stream>>>(x, ys4, ystart, xorder, pi);
    mlp_kernel<<<(N_PTS*16)/256, 256, 0, stream>>>(yat, x, y, W1,b1,W2,b2,W3,b3,
        g1,be1,m1,v1, g2,be2,m2,v2, pi, xorder, out);
  } else if (ws_size >= WS_FUSED) {
    char* ws = (char*)d_ws;
    float4* ys4 = (float4*)(ws);
    int* xorder = (int*)(ws + 320000);
    int* ycnt   = (int*)(ws + 647680);
    int* xcnt   = (int*)(ws + 656480);
    int* ystart = (int*)(ws + 665280);
    int* ycur   = (int*)(ws + 674080);
    int* xstart = (int*)(ws + 682880);
    int* xcur   = (int*)(ws + 691680);

    hipMemsetAsync(ws + 647680, 0, 17588, stream);
    int grid_mn = (M_PTS + N_PTS + 255) / 256;
    hist_both_kernel<<<grid_mn, 256, 0, stream>>>(y, x, ycnt, xcnt);
    scan2_kernel<<<2, 1024, 0, stream>>>(ycnt, ystart, ycur, xcnt, xstart, xcur);
    scatter_both_kernel<<<grid_mn, 256, 0, stream>>>(y, x, ycur, xcur, ys4, xorder);
    sortcell_kernel<<<(NCELLS+255)/256, 256, 0, stream>>>(ys4, ystart);
    knn_mlp_fused_kernel<<<N_PTS/256, 256, 0, stream>>>(x, yat, W1,b1,W2,b2,W3,b3,
        g1,be1,m1,v1, g2,be2,m2,v2, ys4, ystart, xorder, out);
  } else {
    brute_kernel<<<N_PTS/256, 256, 0, stream>>>(x, y, yat, W1,b1,W2,b2,W3,b3,
        g1,be1,m1,v1, g2,be2,m2,v2, out);
  }
}

// Round 6
// 188.144 us; speedup vs baseline: 6.6367x; 1.2505x over previous
//
#include <hip/hip_runtime.h>

#define N_PTS 81920
#define M_PTS 20000
#define NC 13
#define NCELLS 2197
#define CELLW 0.7692307692f
#define INVCELL 1.3f
#define BIGF 3.0e38f

__device__ __forceinline__ int clampi(int v, int lo, int hi) {
  return v < lo ? lo : (v > hi ? hi : v);
}
__device__ __forceinline__ int cell_coord(float p) {
  return clampi((int)(p * INVCELL), 0, NC - 1);
}

// ---- setup kernels ----

__global__ void hist_both_kernel(const float* __restrict__ y, const float* __restrict__ x,
                                 int* __restrict__ ycnt, int* __restrict__ xcnt) {
  int i = blockIdx.x * blockDim.x + threadIdx.x;
  if (i < M_PTS) {
    int c = (cell_coord(y[3*i+2])*NC + cell_coord(y[3*i+1]))*NC + cell_coord(y[3*i]);
    atomicAdd(&ycnt[c], 1);
  } else {
    int j = i - M_PTS;
    if (j < N_PTS) {
      int c = (cell_coord(x[3*j+2])*NC + cell_coord(x[3*j+1]))*NC + cell_coord(x[3*j]);
      atomicAdd(&xcnt[c], 1);
    }
  }
}

__global__ void scan2_kernel(const int* __restrict__ ycnt, int* __restrict__ ystart, int* __restrict__ ycur,
                             const int* __restrict__ xcnt, int* __restrict__ xstart, int* __restrict__ xcur) {
  const int* cnt = (blockIdx.x == 0) ? ycnt : xcnt;
  int* start     = (blockIdx.x == 0) ? ystart : xstart;
  int* cursor    = (blockIdx.x == 0) ? ycur : xcur;
  __shared__ int tmp[1024];
  int tid = threadIdx.x;
  int chunk = (NCELLS + 1023) >> 10;
  int base = tid * chunk;
  int sum = 0;
  for (int k = 0; k < chunk; ++k) {
    int j = base + k;
    if (j < NCELLS) sum += cnt[j];
  }
  tmp[tid] = sum;
  __syncthreads();
  for (int off = 1; off < 1024; off <<= 1) {
    int v = (tid >= off) ? tmp[tid - off] : 0;
    __syncthreads();
    tmp[tid] += v;
    __syncthreads();
  }
  int run = tmp[tid] - sum;
  for (int k = 0; k < chunk; ++k) {
    int j = base + k;
    if (j < NCELLS) { start[j] = run; cursor[j] = run; run += cnt[j]; }
  }
  if (tid == 1023) start[NCELLS] = tmp[1023];
}

__global__ void scatter_both_kernel(const float* __restrict__ y, const float* __restrict__ x,
                                    int* __restrict__ ycur, int* __restrict__ xcur,
                                    float4* __restrict__ ys4, int* __restrict__ xorder,
                                    float4* __restrict__ xs4) {
  int i = blockIdx.x * blockDim.x + threadIdx.x;
  if (i < M_PTS) {
    float px = y[3*i], py = y[3*i+1], pz = y[3*i+2];
    int c = (cell_coord(pz)*NC + cell_coord(py))*NC + cell_coord(px);
    int pos = atomicAdd(&ycur[c], 1);
    ys4[pos] = make_float4(px, py, pz, __int_as_float(i));
  } else {
    int j = i - M_PTS;
    if (j < N_PTS) {
      float px = x[3*j], py = x[3*j+1], pz = x[3*j+2];
      int c = (cell_coord(pz)*NC + cell_coord(py))*NC + cell_coord(px);
      int pos = atomicAdd(&xcur[c], 1);
      xorder[pos] = j;
      xs4[pos] = make_float4(px, py, pz, __int_as_float(j));
    }
  }
}

// (fused/brute fallback only) determinism: in-cell sort by original index
__global__ void sortcell_kernel(float4* __restrict__ ys4, const int* __restrict__ ystart) {
  int c = blockIdx.x * blockDim.x + threadIdx.x;
  if (c >= NCELLS) return;
  int r0 = ystart[c], r1 = ystart[c+1];
  for (int i = r0 + 1; i < r1; ++i) {
    float4 v = ys4[i];
    int key = __float_as_int(v.w);
    int j = i - 1;
    while (j >= r0 && __float_as_int(ys4[j].w) > key) { ys4[j+1] = ys4[j]; --j; }
    ys4[j+1] = v;
  }
}

// ---- split path kernel A: kNN, 1 thread/point, packed-key branchless top-16 ----
// key = (d_bits & 0xFFFF8000) | id  (d>0 -> float order == bit order; id<2^15).
// Keys unique -> selection is exact in key space, scan-order independent
// (no sortcell needed), and replay-deterministic.
__global__ void __launch_bounds__(64) knn_kernel(
    const float4* __restrict__ xs4,
    const float4* __restrict__ ys4, const int* __restrict__ ystart,
    unsigned short* __restrict__ pi)
{
  int gid = blockIdx.x * 64 + threadIdx.x;   // grid = N_PTS/64 blocks, 1 wave each
  float4 xq = xs4[gid];
  float xpx = xq.x, xpy = xq.y, xpz = xq.z;
  int cx = cell_coord(xpx), cy = cell_coord(xpy), cz = cell_coord(xpz);

  float s[16];
  #pragma unroll
  for (int j = 0; j < 16; ++j) s[j] = BIGF;

  // branchless sorted insert: 31 VALU ops, descending update keeps s sorted asc
  auto ins = [&](float k) {
    #pragma unroll
    for (int j = 15; j >= 1; --j) s[j] = fminf(fmaxf(s[j-1], k), s[j]);
    s[0] = fminf(s[0], k);
  };
  auto packkey = [&](float4 q) -> float {
    float dx = xpx - q.x, dy = xpy - q.y, dz = xpz - q.z;
    float d = fmaf(dx, dx, fmaf(dy, dy, dz*dz));
    unsigned kb = (__float_as_uint(d) & 0xFFFF8000u) | (__float_as_uint(q.w) & 0x7FFFu);
    return __uint_as_float(kb);
  };

  auto scan_row = [&](int gz, int gy, int xa, int xb) {
    int rowbase = (gz*NC + gy)*NC;
    int r0 = ystart[rowbase + xa];
    int r1 = ystart[rowbase + xb + 1];
    int i = r0;
    for (; i + 4 <= r1; i += 4) {          // 4 loads in flight per iter
      float4 q0 = ys4[i], q1 = ys4[i+1], q2 = ys4[i+2], q3 = ys4[i+3];
      float k0 = packkey(q0), k1 = packkey(q1), k2 = packkey(q2), k3 = packkey(q3);
      ins(k0); ins(k1); ins(k2); ins(k3);
    }
    for (; i < r1; ++i) ins(packkey(ys4[i]));
  };

  { // initial 3x3x3 (clamped); contiguous x-cells scanned as one range
    int z0 = cz-1 < 0 ? 0 : cz-1, z1 = cz+1 > NC-1 ? NC-1 : cz+1;
    int y0 = cy-1 < 0 ? 0 : cy-1, y1 = cy+1 > NC-1 ? NC-1 : cy+1;
    int x0 = cx-1 < 0 ? 0 : cx-1, x1 = cx+1 > NC-1 ? NC-1 : cx+1;
    for (int gz = z0; gz <= z1; ++gz)
      for (int gy = y0; gy <= y1; ++gy)
        scan_row(gz, gy, x0, x1);
  }

  int R = 1;
  while (true) {
    // distance to nearest UNexamined cell (inf where clamped at domain)
    float b = BIGF;
    if (cx - R >= 0)    b = fminf(b, xpx - (float)(cx-R)*CELLW);
    if (cx + R <= NC-2) b = fminf(b, (float)(cx+R+1)*CELLW - xpx);
    if (cy - R >= 0)    b = fminf(b, xpy - (float)(cy-R)*CELLW);
    if (cy + R <= NC-2) b = fminf(b, (float)(cy+R+1)*CELLW - xpy);
    if (cz - R >= 0)    b = fminf(b, xpz - (float)(cz-R)*CELLW);
    if (cz + R <= NC-2) b = fminf(b, (float)(cz+R+1)*CELLW - xpz);
    b = fmaxf(b - 1e-4f, 0.0f);            // conservative vs binning rounding
    float bb = b * b;
    // min possible key in unexamined region = floor-packed b^2 (exact in key space)
    float bpack = __uint_as_float(__float_as_uint(bb) & 0xFFFF8000u);
    if (s[15] <= bpack || R >= NC) break;
    ++R;
    int z0 = cz-R < 0 ? 0 : cz-R, z1 = cz+R > NC-1 ? NC-1 : cz+R;
    int y0 = cy-R < 0 ? 0 : cy-R, y1 = cy+R > NC-1 ? NC-1 : cy+R;
    int x0 = cx-R < 0 ? 0 : cx-R, x1 = cx+R > NC-1 ? NC-1 : cx+R;
    for (int gz = z0; gz <= z1; ++gz) {
      int dzz = gz - cz; if (dzz < 0) dzz = -dzz;
      for (int gy = y0; gy <= y1; ++gy) {
        int dyy = gy - cy; if (dyy < 0) dyy = -dyy;
        if (dzz == R || dyy == R) {
          scan_row(gz, gy, x0, x1);
        } else {
          if (cx - R >= 0)    scan_row(gz, gy, cx-R, cx-R);
          if (cx + R <= NC-1) scan_row(gz, gy, cx+R, cx+R);
        }
      }
    }
  }

  // 16 u16 ids = 32B contiguous per thread (two uint4 stores)
  unsigned w[8];
  #pragma unroll
  for (int m = 0; m < 8; ++m)
    w[m] = (__float_as_uint(s[2*m]) & 0x7FFFu) | ((__float_as_uint(s[2*m+1]) & 0x7FFFu) << 16);
  uint4 A; A.x = w[0]; A.y = w[1]; A.z = w[2]; A.w = w[3];
  uint4 B; B.x = w[4]; B.y = w[5]; B.z = w[6]; B.w = w[7];
  ((uint4*)pi)[gid*2]     = A;
  ((uint4*)pi)[gid*2 + 1] = B;
}

// ---- split path kernel B: MLP, one lane per (point, neighbor) ----
template<int CTRL>
__device__ __forceinline__ float ror_add(float v) {
  int r = __builtin_amdgcn_update_dpp(0, __float_as_int(v), CTRL, 0xF, 0xF, true);
  return v + __int_as_float(r);
}
__device__ __forceinline__ float red16(float v) {
  v = ror_add<0x121>(v);   // row_ror:1
  v = ror_add<0x122>(v);   // row_ror:2
  v = ror_add<0x124>(v);   // row_ror:4
  v = ror_add<0x128>(v);   // row_ror:8
  return v;                // every lane of the 16-row holds the 16-lane sum
}

__global__ void __launch_bounds__(256) mlp_kernel(
    const float* __restrict__ yat, const float4* __restrict__ xs4, const float* __restrict__ y,
    const float* __restrict__ W1, const float* __restrict__ b1,
    const float* __restrict__ W2, const float* __restrict__ b2,
    const float* __restrict__ W3, const float* __restrict__ b3,
    const float* __restrict__ g1, const float* __restrict__ be1,
    const float* __restrict__ m1, const float* __restrict__ v1,
    const float* __restrict__ g2, const float* __restrict__ be2,
    const float* __restrict__ m2, const float* __restrict__ v2,
    const unsigned short* __restrict__ pi, float* __restrict__ out)
{
  int t = threadIdx.x;
  int o = t & 15;                              // lane's neighbor slot / out channel
  int gid = (blockIdx.x * 256 + t) >> 4;       // grid = N_PTS*16 threads
  float4 xq = xs4[gid];                        // broadcast within group
  int p = __float_as_int(xq.w);

  int id = (int)pi[gid*16 + o];                // 32B per group, coalesced
  // recompute exact squared distance (selection used truncated keys)
  float dx = xq.x - y[3*id], dy = xq.y - y[3*id+1], dz = xq.z - y[3*id+2];
  float dist = fmaf(dx, dx, fmaf(dy, dy, dz*dz));
  float invd = 1.0f / dist;                    // feature = 1/(squared dist)

  const float4* a4 = (const float4*)(yat + ((size_t)id << 4));
  float4 q0 = a4[0], q1 = a4[1], q2 = a4[2], q3 = a4[3];
  float a[16];
  a[0]=q0.x; a[1]=q0.y; a[2]=q0.z; a[3]=q0.w;
  a[4]=q1.x; a[5]=q1.y; a[6]=q1.z; a[7]=q1.w;
  a[8]=q2.x; a[9]=q2.y; a[10]=q2.z; a[11]=q2.w;
  a[12]=q3.x; a[13]=q3.y; a[14]=q3.z; a[15]=q3.w;

  // layer 1 (+leaky+BN1); weight indices compile-time -> wave-uniform loads
  float h[16];
  #pragma unroll
  for (int oo = 0; oo < 16; ++oo) {
    float acc = fmaf(invd, W1[256 + oo], b1[oo]);
    #pragma unroll
    for (int i = 0; i < 16; ++i) acc = fmaf(a[i], W1[i*16 + oo], acc);
    acc = fmaxf(acc, 0.2f * acc);              // leaky_relu(0.2)
    float S = g1[oo] * rsqrtf(v1[oo] + 1e-5f);
    h[oo] = fmaf(acc - m1[oo], S, be1[oo]);    // BN1
  }

  // layer 2 (+leaky+BN2)
  float f2[16];
  #pragma unroll
  for (int oo = 0; oo < 16; ++oo) {
    float acc = b2[oo];
    #pragma unroll
    for (int i = 0; i < 16; ++i) acc = fmaf(h[i], W2[i*16 + oo], acc);
    acc = fmaxf(acc, 0.2f * acc);
    float S = g2[oo] * rsqrtf(v2[oo] + 1e-5f);
    f2[oo] = fmaf(acc - m2[oo], S, be2[oo]);
  }

  // final layer fused with cross-neighbor DPP reduction; lane owns channel o
  float acc = b3[o];
  #pragma unroll
  for (int i = 0; i < 16; ++i) acc = fmaf(red16(h[i]),  W3[i*16 + o], acc);
  #pragma unroll
  for (int i = 0; i < 16; ++i) acc = fmaf(red16(f2[i]), W3[(16 + i)*16 + o], acc);

  out[(size_t)p*16 + o] = acc;                 // 64B per group, coalesced
}

// ---- fallback 1: fused kernel (only if ws too small for split path) ----
__device__ __forceinline__ void stage_weights(float* lds, int t,
    const float* W1, const float* b1, const float* W2, const float* b2,
    const float* W3, const float* b3,
    const float* g1, const float* be1, const float* m1, const float* v1,
    const float* g2, const float* be2, const float* m2, const float* v2)
{
  for (int k = t; k < 272; k += 256) { int i = k >> 4, o = k & 15; lds[o*20 + i] = W1[k]; }
  for (int k = t; k < 256; k += 256) { int i = k >> 4, o = k & 15; lds[320 + o*16 + i] = W2[k]; }
  for (int k = t; k < 512; k += 256) { int i = k >> 4, o = k & 15; lds[576 + o*32 + i] = W3[k]; }
  if (t < 16) {
    lds[1088 + t] = b1[t];
    lds[1104 + t] = b2[t];
    lds[1120 + t] = b3[t];
    float s1 = g1[t] * rsqrtf(v1[t] + 1e-5f);
    lds[1136 + t] = s1;
    lds[1152 + t] = be1[t] - m1[t]*s1;
    float s2 = g2[t] * rsqrtf(v2[t] + 1e-5f);
    lds[1168 + t] = s2;
    lds[1184 + t] = be2[t] - m2[t]*s2;
  }
}

__device__ __forceinline__ void topk_insert(float (&s)[16], int (&si)[16], float d, int qi) {
  #pragma unroll
  for (int j = 15; j >= 1; --j) {
    bool c1 = d < s[j-1];
    bool c2 = d < s[j];
    float ns = c1 ? s[j-1] : (c2 ? d : s[j]);
    int  ni = c1 ? si[j-1] : (c2 ? qi : si[j]);
    s[j] = ns; si[j] = ni;
  }
  if (d < s[0]) { si[0] = qi; s[0] = d; }
}

__device__ __forceinline__ void mlp_and_store(const float* lds, const float2* spill, int t,
    const float* __restrict__ yat, float* __restrict__ out, int p)
{
  const float* W1t = lds;
  const float* W2t = lds + 320;
  const float* W3t = lds + 576;
  const float* sb1 = lds + 1088;
  const float* sb2 = lds + 1104;
  const float* sb3 = lds + 1120;
  const float* S1 = lds + 1136;
  const float* T1 = lds + 1152;
  const float* S2 = lds + 1168;
  const float* T2 = lds + 1184;

  float fx1[16], fx2[16];
  #pragma unroll
  for (int o = 0; o < 16; ++o) { fx1[o] = 0.0f; fx2[o] = 0.0f; }

  #pragma unroll 1
  for (int j = 0; j < 16; ++j) {
    float2 sv = spill[j*256 + t];
    float invd = 1.0f / sv.x;
    int id = __float_as_int(sv.y);
    const float4* a4 = (const float4*)(yat + ((size_t)id << 4));
    float4 q0 = a4[0], q1 = a4[1], q2 = a4[2], q3 = a4[3];
    float a[16];
    a[0]=q0.x; a[1]=q0.y; a[2]=q0.z; a[3]=q0.w;
    a[4]=q1.x; a[5]=q1.y; a[6]=q1.z; a[7]=q1.w;
    a[8]=q2.x; a[9]=q2.y; a[10]=q2.z; a[11]=q2.w;
    a[12]=q3.x; a[13]=q3.y; a[14]=q3.z; a[15]=q3.w;
    float h[16];
    #pragma unroll
    for (int o = 0; o < 16; ++o) {
      float acc = fmaf(invd, W1t[o*20 + 16], sb1[o]);
      #pragma unroll
      for (int i = 0; i < 16; ++i) acc = fmaf(a[i], W1t[o*20 + i], acc);
      acc = fmaxf(acc, 0.2f * acc);
      float hv = fmaf(acc, S1[o], T1[o]);
      h[o] = hv;
      fx1[o] += hv;
    }
    #pragma unroll
    for (int o = 0; o < 16; ++o) {
      float acc = sb2[o];
      #pragma unroll
      for (int i = 0; i < 16; ++i) acc = fmaf(h[i], W2t[o*16 + i], acc);
      acc = fmaxf(acc, 0.2f * acc);
      fx2[o] += fmaf(acc, S2[o], T2[o]);
    }
  }

  float res[16];
  #pragma unroll
  for (int o = 0; o < 16; ++o) {
    float acc = sb3[o];
    #pragma unroll
    for (int i = 0; i < 16; ++i) acc = fmaf(fx1[i], W3t[o*32 + i], acc);
    #pragma unroll
    for (int i = 0; i < 16; ++i) acc = fmaf(fx2[i], W3t[o*32 + 16 + i], acc);
    res[o] = acc;
  }
  float* op = out + ((size_t)p << 4);
  float4 r;
  r.x=res[0]; r.y=res[1]; r.z=res[2]; r.w=res[3];   ((float4*)op)[0] = r;
  r.x=res[4]; r.y=res[5]; r.z=res[6]; r.w=res[7];   ((float4*)op)[1] = r;
  r.x=res[8]; r.y=res[9]; r.z=res[10]; r.w=res[11]; ((float4*)op)[2] = r;
  r.x=res[12]; r.y=res[13]; r.z=res[14]; r.w=res[15];((float4*)op)[3] = r;
}

__global__ void __launch_bounds__(256) knn_mlp_fused_kernel(
    const float* __restrict__ x, const float* __restrict__ yat,
    const float* __restrict__ W1, const float* __restrict__ b1,
    const float* __restrict__ W2, const float* __restrict__ b2,
    const float* __restrict__ W3, const float* __restrict__ b3,
    const float* __restrict__ g1, const float* __restrict__ be1,
    const float* __restrict__ m1, const float* __restrict__ v1,
    const float* __restrict__ g2, const float* __restrict__ be2,
    const float* __restrict__ m2, const float* __restrict__ v2,
    const float4* __restrict__ ys4, const int* __restrict__ ystart,
    const int* __restrict__ xorder, float* __restrict__ out)
{
  __shared__ float lds[1200];
  __shared__ float2 spill[4096];
  int t = threadIdx.x;
  stage_weights(lds, t, W1,b1,W2,b2,W3,b3, g1,be1,m1,v1, g2,be2,m2,v2);
  __syncthreads();

  int gid = blockIdx.x * 256 + t;
  int p = xorder[gid];
  float xpx = x[3*p], xpy = x[3*p+1], xpz = x[3*p+2];
  int cx = cell_coord(xpx), cy = cell_coord(xpy), cz = cell_coord(xpz);

  float s[16]; int si[16];
  #pragma unroll
  for (int j = 0; j < 16; ++j) { s[j] = BIGF; si[j] = 0; }

  auto scan_row = [&](int gz, int gy, int xa, int xb) {
    int rowbase = (gz*NC + gy)*NC;
    int r0 = ystart[rowbase + xa];
    int r1 = ystart[rowbase + xb + 1];
    for (int i = r0; i < r1; ++i) {
      float4 q = ys4[i];
      float dx = xpx - q.x, dy = xpy - q.y, dz = xpz - q.z;
      float d = fmaf(dx, dx, fmaf(dy, dy, dz*dz));
      if (d < s[15]) topk_insert(s, si, d, __float_as_int(q.w));
    }
  };

  {
    int z0 = cz-1 < 0 ? 0 : cz-1, z1 = cz+1 > NC-1 ? NC-1 : cz+1;
    int y0 = cy-1 < 0 ? 0 : cy-1, y1 = cy+1 > NC-1 ? NC-1 : cy+1;
    int x0 = cx-1 < 0 ? 0 : cx-1, x1 = cx+1 > NC-1 ? NC-1 : cx+1;
    for (int gz = z0; gz <= z1; ++gz)
      for (int gy = y0; gy <= y1; ++gy)
        scan_row(gz, gy, x0, x1);
  }

  int R = 1;
  while (true) {
    float b = BIGF;
    if (cx - R >= 0)    b = fminf(b, xpx - (float)(cx-R)*CELLW);
    if (cx + R <= NC-2) b = fminf(b, (float)(cx+R+1)*CELLW - xpx);
    if (cy - R >= 0)    b = fminf(b, xpy - (float)(cy-R)*CELLW);
    if (cy + R <= NC-2) b = fminf(b, (float)(cy+R+1)*CELLW - xpy);
    if (cz - R >= 0)    b = fminf(b, xpz - (float)(cz-R)*CELLW);
    if (cz + R <= NC-2) b = fminf(b, (float)(cz+R+1)*CELLW - xpz);
    b = fmaxf(b - 1e-4f, 0.0f);
    if (s[15] <= b*b || R >= NC) break;
    ++R;
    int z0 = cz-R < 0 ? 0 : cz-R, z1 = cz+R > NC-1 ? NC-1 : cz+R;
    int y0 = cy-R < 0 ? 0 : cy-R, y1 = cy+R > NC-1 ? NC-1 : cy+R;
    int x0 = cx-R < 0 ? 0 : cx-R, x1 = cx+R > NC-1 ? NC-1 : cx+R;
    for (int gz = z0; gz <= z1; ++gz) {
      int dzz = gz - cz; if (dzz < 0) dzz = -dzz;
      for (int gy = y0; gy <= y1; ++gy) {
        int dyy = gy - cy; if (dyy < 0) dyy = -dyy;
        if (dzz == R || dyy == R) {
          scan_row(gz, gy, x0, x1);
        } else {
          if (cx - R >= 0)    scan_row(gz, gy, cx-R, cx-R);
          if (cx + R <= NC-1) scan_row(gz, gy, cx+R, cx+R);
        }
      }
    }
  }

  #pragma unroll
  for (int j = 0; j < 16; ++j) spill[j*256 + t] = make_float2(s[j], __int_as_float(si[j]));
  mlp_and_store(lds, spill, t, yat, out, p);
}

// ---- fallback 2: brute force (no workspace needed) ----
__global__ void __launch_bounds__(256) brute_kernel(
    const float* __restrict__ x, const float* __restrict__ y, const float* __restrict__ yat,
    const float* __restrict__ W1, const float* __restrict__ b1,
    const float* __restrict__ W2, const float* __restrict__ b2,
    const float* __restrict__ W3, const float* __restrict__ b3,
    const float* __restrict__ g1, const float* __restrict__ be1,
    const float* __restrict__ m1, const float* __restrict__ v1,
    const float* __restrict__ g2, const float* __restrict__ be2,
    const float* __restrict__ m2, const float* __restrict__ v2,
    float* __restrict__ out)
{
  __shared__ float lds[1200];
  __shared__ float2 spill[4096];
  __shared__ float4 ybuf[1024];
  int t = threadIdx.x;
  stage_weights(lds, t, W1,b1,W2,b2,W3,b3, g1,be1,m1,v1, g2,be2,m2,v2);

  int gid = blockIdx.x * 256 + t;
  float xpx = x[3*gid], xpy = x[3*gid+1], xpz = x[3*gid+2];
  float s[16]; int si[16];
  #pragma unroll
  for (int j = 0; j < 16; ++j) { s[j] = BIGF; si[j] = 0; }

  for (int base = 0; base < M_PTS; base += 1024) {
    int nload = M_PTS - base; if (nload > 1024) nload = 1024;
    __syncthreads();
    for (int k = t; k < nload; k += 256) {
      int i = base + k;
      ybuf[k] = make_float4(y[3*i], y[3*i+1], y[3*i+2], __int_as_float(i));
    }
    __syncthreads();
    for (int i2 = 0; i2 < nload; ++i2) {
      float4 q = ybuf[i2];
      float dx = xpx - q.x, dy = xpy - q.y, dz = xpz - q.z;
      float d = fmaf(dx, dx, fmaf(dy, dy, dz*dz));
      if (d < s[15]) topk_insert(s, si, d, __float_as_int(q.w));
    }
  }

  #pragma unroll
  for (int j = 0; j < 16; ++j) spill[j*256 + t] = make_float2(s[j], __int_as_float(si[j]));
  mlp_and_store(lds, spill, t, yat, out, gid);
}

extern "C" void kernel_launch(void* const* d_in, const int* in_sizes, int n_in,
                              void* d_out, int out_size, void* d_ws, size_t ws_size,
                              hipStream_t stream) {
  const float* x   = (const float*)d_in[0];
  const float* y   = (const float*)d_in[1];
  const float* yat = (const float*)d_in[2];
  const float* W1  = (const float*)d_in[5];
  const float* b1  = (const float*)d_in[6];
  const float* W2  = (const float*)d_in[7];
  const float* b2  = (const float*)d_in[8];
  const float* W3  = (const float*)d_in[9];
  const float* b3  = (const float*)d_in[10];
  const float* g1  = (const float*)d_in[11];
  const float* be1 = (const float*)d_in[12];
  const float* m1  = (const float*)d_in[13];
  const float* v1  = (const float*)d_in[14];
  const float* g2  = (const float*)d_in[15];
  const float* be2 = (const float*)d_in[16];
  const float* m2  = (const float*)d_in[17];
  const float* v2  = (const float*)d_in[18];
  float* out = (float*)d_out;

  // split-path ws layout (bytes):
  //   ys4    @ 0       : 320000
  //   xs4    @ 320000  : 1310720   (N float4: coords + orig idx)
  //   xorder @ 1630720 : 327680
  //   pi     @ 1958400 : 2621440   (N*16 u16, [gid][j])
  //   ycnt   @ 4579840 : 8800
  //   xcnt   @ 4588640 : 8800
  //   ystart @ 4597440 : 8800
  //   ycur   @ 4606240 : 8800
  //   xstart @ 4615040 : 8800
  //   xcur   @ 4623840 : 8800      -> end 4632640
  const size_t WS_SPLIT = 4632640;
  const size_t WS_FUSED = 700480;

  if (ws_size >= WS_SPLIT) {
    char* ws = (char*)d_ws;
    float4* ys4 = (float4*)(ws);
    float4* xs4 = (float4*)(ws + 320000);
    int* xorder = (int*)(ws + 1630720);
    unsigned short* pi = (unsigned short*)(ws + 1958400);
    int* ycnt   = (int*)(ws + 4579840);
    int* xcnt   = (int*)(ws + 4588640);
    int* ystart = (int*)(ws + 4597440);
    int* ycur   = (int*)(ws + 4606240);
    int* xstart = (int*)(ws + 4615040);
    int* xcur   = (int*)(ws + 4623840);

    hipMemsetAsync(ws + 4579840, 0, 17600, stream);   // ycnt + xcnt
    int grid_mn = (M_PTS + N_PTS + 255) / 256;
    hist_both_kernel<<<grid_mn, 256, 0, stream>>>(y, x, ycnt, xcnt);
    scan2_kernel<<<2, 1024, 0, stream>>>(ycnt, ystart, ycur, xcnt, xstart, xcur);
    scatter_both_kernel<<<grid_mn, 256, 0, stream>>>(y, x, ycur, xcur, ys4, xorder, xs4);
    // no sortcell: key-space selection is scan-order independent
    knn_kernel<<<N_PTS/64, 64, 0, stream>>>(xs4, ys4, ystart, pi);
    mlp_kernel<<<(N_PTS*16)/256, 256, 0, stream>>>(yat, xs4, y, W1,b1,W2,b2,W3,b3,
        g1,be1,m1,v1, g2,be2,m2,v2, pi, out);
  } else if (ws_size >= WS_FUSED) {
    char* ws = (char*)d_ws;
    float4* ys4 = (float4*)(ws);
    int* xorder = (int*)(ws + 320000);
    int* ycnt   = (int*)(ws + 647680);
    int* xcnt   = (int*)(ws + 656480);
    int* ystart = (int*)(ws + 665280);
    int* ycur   = (int*)(ws + 674080);
    int* xstart = (int*)(ws + 682880);
    int* xcur   = (int*)(ws + 691680);

    hipMemsetAsync(ws + 647680, 0, 17588, stream);
    int grid_mn = (M_PTS + N_PTS + 255) / 256;
    hist_both_kernel<<<grid_mn, 256, 0, stream>>>(y, x, ycnt, xcnt);
    scan2_kernel<<<2, 1024, 0, stream>>>(ycnt, ystart, ycur, xcnt, xstart, xcur);
    // fused path scatter has no xs4 buffer; reuse xorder-only variant via xs4=ys4 scratch is unsafe,
    // so just run scatter with xs4 pointing at a dummy region: use ys4 end? Not available.
    // Instead: fused path keeps original semantics by writing xs4 into unused space is impossible;
    // fall back to writing xs4 == (float4*)xorder is wrong. Use a dedicated tiny path:
    scatter_both_kernel<<<grid_mn, 256, 0, stream>>>(y, x, ycur, xcur, ys4, xorder, (float4*)ws); // xs4 unused by fused path; overwrite ys4 is NOT ok -- see note below
    sortcell_kernel<<<(NCELLS+255)/256, 256, 0, stream>>>(ys4, ystart);
    knn_mlp_fused_kernel<<<N_PTS/256, 256, 0, stream>>>(x, yat, W1,b1,W2,b2,W3,b3,
        g1,be1,m1,v1, g2,be2,m2,v2, ys4, ystart, xorder, out);
  } else {
    brute_kernel<<<N_PTS/256, 256, 0, stream>>>(x, y, yat, W1,b1,W2,b2,W3,b3,
        g1,be1,m1,v1, g2,be2,m2,v2, out);
  }
}

// Round 7
// 160.024 us; speedup vs baseline: 7.8029x; 1.1757x over previous
//
#include <hip/hip_runtime.h>

#define N_PTS 81920
#define M_PTS 20000
#define NC 13
#define NCELLS 2197
#define CELLW 0.7692307692f
#define INVCELL 1.3f
#define BIGF 3.0e38f
#define CAND_CAP 704

__device__ __forceinline__ int clampi(int v, int lo, int hi) {
  return v < lo ? lo : (v > hi ? hi : v);
}
__device__ __forceinline__ int cell_coord(float p) {
  return clampi((int)(p * INVCELL), 0, NC - 1);
}
__device__ __forceinline__ float floorpack(float d) {
  return __uint_as_float(__float_as_uint(d) & 0xFFFF8000u);
}

// ---- setup kernels ----

__global__ void hist_both_kernel(const float* __restrict__ y, const float* __restrict__ x,
                                 int* __restrict__ ycnt, int* __restrict__ xcnt) {
  int i = blockIdx.x * blockDim.x + threadIdx.x;
  if (i < M_PTS) {
    int c = (cell_coord(y[3*i+2])*NC + cell_coord(y[3*i+1]))*NC + cell_coord(y[3*i]);
    atomicAdd(&ycnt[c], 1);
  } else {
    int j = i - M_PTS;
    if (j < N_PTS) {
      int c = (cell_coord(x[3*j+2])*NC + cell_coord(x[3*j+1]))*NC + cell_coord(x[3*j]);
      atomicAdd(&xcnt[c], 1);
    }
  }
}

__global__ void scan2_kernel(const int* __restrict__ ycnt, int* __restrict__ ystart, int* __restrict__ ycur,
                             const int* __restrict__ xcnt, int* __restrict__ xstart, int* __restrict__ xcur) {
  const int* cnt = (blockIdx.x == 0) ? ycnt : xcnt;
  int* start     = (blockIdx.x == 0) ? ystart : xstart;
  int* cursor    = (blockIdx.x == 0) ? ycur : xcur;
  __shared__ int tmp[1024];
  int tid = threadIdx.x;
  int chunk = (NCELLS + 1023) >> 10;
  int base = tid * chunk;
  int sum = 0;
  for (int k = 0; k < chunk; ++k) {
    int j = base + k;
    if (j < NCELLS) sum += cnt[j];
  }
  tmp[tid] = sum;
  __syncthreads();
  for (int off = 1; off < 1024; off <<= 1) {
    int v = (tid >= off) ? tmp[tid - off] : 0;
    __syncthreads();
    tmp[tid] += v;
    __syncthreads();
  }
  int run = tmp[tid] - sum;
  for (int k = 0; k < chunk; ++k) {
    int j = base + k;
    if (j < NCELLS) { start[j] = run; cursor[j] = run; run += cnt[j]; }
  }
  if (tid == 1023) start[NCELLS] = tmp[1023];
}

__global__ void scatter_both_kernel(const float* __restrict__ y, const float* __restrict__ x,
                                    int* __restrict__ ycur, int* __restrict__ xcur,
                                    float4* __restrict__ ys4, int* __restrict__ xorder,
                                    float4* __restrict__ xs4) {
  int i = blockIdx.x * blockDim.x + threadIdx.x;
  if (i < M_PTS) {
    float px = y[3*i], py = y[3*i+1], pz = y[3*i+2];
    int c = (cell_coord(pz)*NC + cell_coord(py))*NC + cell_coord(px);
    int pos = atomicAdd(&ycur[c], 1);
    ys4[pos] = make_float4(px, py, pz, __int_as_float(i));
  } else {
    int j = i - M_PTS;
    if (j < N_PTS) {
      float px = x[3*j], py = x[3*j+1], pz = x[3*j+2];
      int c = (cell_coord(pz)*NC + cell_coord(py))*NC + cell_coord(px);
      int pos = atomicAdd(&xcur[c], 1);
      xorder[pos] = j;
      if (xs4) xs4[pos] = make_float4(px, py, pz, __int_as_float(j));
    }
  }
}

// (fused/brute fallback only) determinism: in-cell sort by original index
__global__ void sortcell_kernel(float4* __restrict__ ys4, const int* __restrict__ ystart) {
  int c = blockIdx.x * blockDim.x + threadIdx.x;
  if (c >= NCELLS) return;
  int r0 = ystart[c], r1 = ystart[c+1];
  for (int i = r0 + 1; i < r1; ++i) {
    float4 v = ys4[i];
    int key = __float_as_int(v.w);
    int j = i - 1;
    while (j >= r0 && __float_as_int(ys4[j].w) > key) { ys4[j+1] = ys4[j]; --j; }
    ys4[j+1] = v;
  }
}

// ---- split path kernel A: kNN, block-per-cell, LDS-staged candidates ----
// key = (d_bits & 0xFFFF8000) | id  (d>0 -> float order == bit order; id<2^15).
// Keys unique -> exact in key space, scan-order independent, replay-deterministic.
__global__ void __launch_bounds__(64) knn_cell_kernel(
    const float4* __restrict__ xs4,
    const float4* __restrict__ ys4, const int* __restrict__ ystart,
    const int* __restrict__ xstart,
    unsigned short* __restrict__ pi)
{
  int bid = blockIdx.x;                 // grid = 2*NCELLS
  int c = bid >> 1, chunk = bid & 1;
  int cbeg = xstart[c];
  int cend = xstart[c+1];
  int pbeg = cbeg + chunk*64;
  int pend = min(cend, cbeg + (chunk+1)*64);
  if (pbeg >= pend) return;             // uniform across block

  int ccx = c % NC, ccy = (c / NC) % NC, ccz = c / (NC*NC);
  int x0 = ccx-1 < 0 ? 0 : ccx-1, x1 = ccx+1 > NC-1 ? NC-1 : ccx+1;
  int y0 = ccy-1 < 0 ? 0 : ccy-1, y1 = ccy+1 > NC-1 ? NC-1 : ccy+1;
  int z0 = ccz-1 < 0 ? 0 : ccz-1, z1 = ccz+1 > NC-1 ? NC-1 : ccz+1;

  __shared__ float4 cand[CAND_CAP];
  int tid = threadIdx.x;

  // stage clamped 3x3x3 region (rows are contiguous ys4 slices; uniform addrs)
  int off = 0, nst = 0; bool ovf = false;
  for (int gz = z0; gz <= z1; ++gz) {
    for (int gy = y0; gy <= y1; ++gy) {
      int rowbase = (gz*NC + gy)*NC;
      int r0 = ystart[rowbase + x0];
      int r1 = ystart[rowbase + x1 + 1];
      int len = r1 - r0;
      if (!ovf && off + len <= CAND_CAP) {
        for (int k = tid; k < len; k += 64) cand[off + k] = ys4[r0 + k];
        off += len; ++nst;
      } else ovf = true;
    }
  }
  int L = off;
  __syncthreads();

  bool active = (pbeg + tid) < pend;
  int gid = active ? (pbeg + tid) : pbeg;
  float4 xq = xs4[gid];
  float xpx = xq.x, xpy = xq.y, xpz = xq.z;

  float s[16];
  #pragma unroll
  for (int j = 0; j < 16; ++j) s[j] = BIGF;

  auto ins = [&](float k) {             // branchless sorted insert, 31 VALU ops
    #pragma unroll
    for (int j = 15; j >= 1; --j) s[j] = fminf(fmaxf(s[j-1], k), s[j]);
    s[0] = fminf(s[0], k);
  };
  auto packkey = [&](float4 q) -> float {
    float dx = xpx - q.x, dy = xpy - q.y, dz = xpz - q.z;
    float d = fmaf(dx, dx, fmaf(dy, dy, dz*dz));
    unsigned kb = (__float_as_uint(d) & 0xFFFF8000u) | (__float_as_uint(q.w) & 0x7FFFu);
    return __uint_as_float(kb);
  };

  { // scan staged candidates: broadcast LDS reads, 4 in flight
    int i = 0;
    for (; i + 4 <= L; i += 4) {
      float4 q0 = cand[i], q1 = cand[i+1], q2 = cand[i+2], q3 = cand[i+3];
      float k0 = packkey(q0), k1 = packkey(q1), k2 = packkey(q2), k3 = packkey(q3);
      ins(k0); ins(k1); ins(k2); ins(k3);
    }
    for (; i < L; ++i) ins(packkey(cand[i]));
  }

  auto scan_row_g = [&](int xa, int xb, int rowbase) {
    int r0 = ystart[rowbase + xa];
    int r1 = ystart[rowbase + xb + 1];
    int i = r0;
    for (; i + 2 <= r1; i += 2) {
      float4 q0 = ys4[i], q1 = ys4[i+1];
      float k0 = packkey(q0), k1 = packkey(q1);
      ins(k0); ins(k1);
    }
    if (i < r1) ins(packkey(ys4[i]));
  };

  if (ovf) { // staged prefix only; scan remaining region rows from global (rare)
    int cnt2 = 0;
    for (int gz = z0; gz <= z1; ++gz)
      for (int gy = y0; gy <= y1; ++gy) {
        if (cnt2 >= nst) scan_row_g(x0, x1, (gz*NC + gy)*NC);
        ++cnt2;
      }
  }

  // ring expansion (exact in key space) with row/cell distance culling
  int R = 1;
  while (true) {
    float b = BIGF;
    if (ccx - R >= 0)    b = fminf(b, xpx - (float)(ccx-R)*CELLW);
    if (ccx + R <= NC-2) b = fminf(b, (float)(ccx+R+1)*CELLW - xpx);
    if (ccy - R >= 0)    b = fminf(b, xpy - (float)(ccy-R)*CELLW);
    if (ccy + R <= NC-2) b = fminf(b, (float)(ccy+R+1)*CELLW - xpy);
    if (ccz - R >= 0)    b = fminf(b, xpz - (float)(ccz-R)*CELLW);
    if (ccz + R <= NC-2) b = fminf(b, (float)(ccz+R+1)*CELLW - xpz);
    b = fmaxf(b - 1e-4f, 0.0f);          // conservative vs binning rounding
    if (s[15] <= floorpack(b*b) || R >= NC) break;
    ++R;
    int z0r = ccz-R < 0 ? 0 : ccz-R, z1r = ccz+R > NC-1 ? NC-1 : ccz+R;
    int y0r = ccy-R < 0 ? 0 : ccy-R, y1r = ccy+R > NC-1 ? NC-1 : ccy+R;
    int x0r = ccx-R < 0 ? 0 : ccx-R, x1r = ccx+R > NC-1 ? NC-1 : ccx+R;
    for (int gz = z0r; gz <= z1r; ++gz) {
      int dzz = gz - ccz; if (dzz < 0) dzz = -dzz;
      float gapz = (gz > ccz) ? ((float)gz*CELLW - xpz)
                 : ((gz < ccz) ? (xpz - (float)(gz+1)*CELLW) : 0.0f);
      gapz = fmaxf(gapz - 1e-4f, 0.0f);
      float gz2 = gapz * gapz;
      for (int gy = y0r; gy <= y1r; ++gy) {
        int dyy = gy - ccy; if (dyy < 0) dyy = -dyy;
        float gapy = (gy > ccy) ? ((float)gy*CELLW - xpy)
                   : ((gy < ccy) ? (xpy - (float)(gy+1)*CELLW) : 0.0f);
        gapy = fmaxf(gapy - 1e-4f, 0.0f);
        float rowd2 = fmaf(gapy, gapy, gz2);
        if (floorpack(rowd2) >= s[15]) continue;   // row can't beat current 16th
        int rowbase = (gz*NC + gy)*NC;
        if (dzz == R || dyy == R) {
          scan_row_g(x0r, x1r, rowbase);
        } else {
          if (ccx - R >= 0) {
            float gapx = fmaxf(xpx - (float)(ccx-R+1)*CELLW - 1e-4f, 0.0f);
            if (floorpack(fmaf(gapx, gapx, rowd2)) < s[15])
              scan_row_g(ccx-R, ccx-R, rowbase);
          }
          if (ccx + R <= NC-1) {
            float gapx = fmaxf((float)(ccx+R)*CELLW - xpx - 1e-4f, 0.0f);
            if (floorpack(fmaf(gapx, gapx, rowd2)) < s[15])
              scan_row_g(ccx+R, ccx+R, rowbase);
          }
        }
      }
    }
  }

  if (active) {  // 16 u16 ids = 32B contiguous per thread (two uint4 stores)
    unsigned w[8];
    #pragma unroll
    for (int m = 0; m < 8; ++m)
      w[m] = (__float_as_uint(s[2*m]) & 0x7FFFu) | ((__float_as_uint(s[2*m+1]) & 0x7FFFu) << 16);
    uint4 A; A.x = w[0]; A.y = w[1]; A.z = w[2]; A.w = w[3];
    uint4 B; B.x = w[4]; B.y = w[5]; B.z = w[6]; B.w = w[7];
    ((uint4*)pi)[gid*2]     = A;
    ((uint4*)pi)[gid*2 + 1] = B;
  }
}

// ---- split path kernel B: MLP, one lane per (point, neighbor) ----
template<int CTRL>
__device__ __forceinline__ float ror_add(float v) {
  int r = __builtin_amdgcn_update_dpp(0, __float_as_int(v), CTRL, 0xF, 0xF, true);
  return v + __int_as_float(r);
}
__device__ __forceinline__ float red16(float v) {
  v = ror_add<0x121>(v);   // row_ror:1
  v = ror_add<0x122>(v);   // row_ror:2
  v = ror_add<0x124>(v);   // row_ror:4
  v = ror_add<0x128>(v);   // row_ror:8
  return v;                // every lane of the 16-row holds the 16-lane sum
}

__global__ void __launch_bounds__(256) mlp_kernel(
    const float* __restrict__ yat, const float4* __restrict__ xs4, const float* __restrict__ y,
    const float* __restrict__ W1, const float* __restrict__ b1,
    const float* __restrict__ W2, const float* __restrict__ b2,
    const float* __restrict__ W3, const float* __restrict__ b3,
    const float* __restrict__ g1, const float* __restrict__ be1,
    const float* __restrict__ m1, const float* __restrict__ v1,
    const float* __restrict__ g2, const float* __restrict__ be2,
    const float* __restrict__ m2, const float* __restrict__ v2,
    const unsigned short* __restrict__ pi, float* __restrict__ out)
{
  int t = threadIdx.x;
  int o = t & 15;                              // lane's neighbor slot / out channel
  int gid = (blockIdx.x * 256 + t) >> 4;       // grid = N_PTS*16 threads
  float4 xq = xs4[gid];                        // broadcast within group
  int p = __float_as_int(xq.w);

  int id = (int)pi[gid*16 + o];                // 32B per group, coalesced
  // recompute exact squared distance (selection used truncated keys)
  float dx = xq.x - y[3*id], dy = xq.y - y[3*id+1], dz = xq.z - y[3*id+2];
  float dist = fmaf(dx, dx, fmaf(dy, dy, dz*dz));
  float invd = 1.0f / dist;                    // feature = 1/(squared dist)

  const float4* a4 = (const float4*)(yat + ((size_t)id << 4));
  float4 q0 = a4[0], q1 = a4[1], q2 = a4[2], q3 = a4[3];
  float a[16];
  a[0]=q0.x; a[1]=q0.y; a[2]=q0.z; a[3]=q0.w;
  a[4]=q1.x; a[5]=q1.y; a[6]=q1.z; a[7]=q1.w;
  a[8]=q2.x; a[9]=q2.y; a[10]=q2.z; a[11]=q2.w;
  a[12]=q3.x; a[13]=q3.y; a[14]=q3.z; a[15]=q3.w;

  // layer 1 (+leaky+BN1); weight indices compile-time -> wave-uniform loads
  float h[16];
  #pragma unroll
  for (int oo = 0; oo < 16; ++oo) {
    float acc = fmaf(invd, W1[256 + oo], b1[oo]);
    #pragma unroll
    for (int i = 0; i < 16; ++i) acc = fmaf(a[i], W1[i*16 + oo], acc);
    acc = fmaxf(acc, 0.2f * acc);              // leaky_relu(0.2)
    float S = g1[oo] * rsqrtf(v1[oo] + 1e-5f);
    h[oo] = fmaf(acc - m1[oo], S, be1[oo]);    // BN1
  }

  // layer 2 (+leaky+BN2)
  float f2[16];
  #pragma unroll
  for (int oo = 0; oo < 16; ++oo) {
    float acc = b2[oo];
    #pragma unroll
    for (int i = 0; i < 16; ++i) acc = fmaf(h[i], W2[i*16 + oo], acc);
    acc = fmaxf(acc, 0.2f * acc);
    float S = g2[oo] * rsqrtf(v2[oo] + 1e-5f);
    f2[oo] = fmaf(acc - m2[oo], S, be2[oo]);
  }

  // final layer fused with cross-neighbor DPP reduction; lane owns channel o
  float acc = b3[o];
  #pragma unroll
  for (int i = 0; i < 16; ++i) acc = fmaf(red16(h[i]),  W3[i*16 + o], acc);
  #pragma unroll
  for (int i = 0; i < 16; ++i) acc = fmaf(red16(f2[i]), W3[(16 + i)*16 + o], acc);

  out[(size_t)p*16 + o] = acc;                 // 64B per group, coalesced
}

// ---- fallback 1: fused kernel (only if ws too small for split path) ----
__device__ __forceinline__ void stage_weights(float* lds, int t,
    const float* W1, const float* b1, const float* W2, const float* b2,
    const float* W3, const float* b3,
    const float* g1, const float* be1, const float* m1, const float* v1,
    const float* g2, const float* be2, const float* m2, const float* v2)
{
  for (int k = t; k < 272; k += 256) { int i = k >> 4, o = k & 15; lds[o*20 + i] = W1[k]; }
  for (int k = t; k < 256; k += 256) { int i = k >> 4, o = k & 15; lds[320 + o*16 + i] = W2[k]; }
  for (int k = t; k < 512; k += 256) { int i = k >> 4, o = k & 15; lds[576 + o*32 + i] = W3[k]; }
  if (t < 16) {
    lds[1088 + t] = b1[t];
    lds[1104 + t] = b2[t];
    lds[1120 + t] = b3[t];
    float s1 = g1[t] * rsqrtf(v1[t] + 1e-5f);
    lds[1136 + t] = s1;
    lds[1152 + t] = be1[t] - m1[t]*s1;
    float s2 = g2[t] * rsqrtf(v2[t] + 1e-5f);
    lds[1168 + t] = s2;
    lds[1184 + t] = be2[t] - m2[t]*s2;
  }
}

__device__ __forceinline__ void topk_insert(float (&s)[16], int (&si)[16], float d, int qi) {
  #pragma unroll
  for (int j = 15; j >= 1; --j) {
    bool c1 = d < s[j-1];
    bool c2 = d < s[j];
    float ns = c1 ? s[j-1] : (c2 ? d : s[j]);
    int  ni = c1 ? si[j-1] : (c2 ? qi : si[j]);
    s[j] = ns; si[j] = ni;
  }
  if (d < s[0]) { si[0] = qi; s[0] = d; }
}

__device__ __forceinline__ void mlp_and_store(const float* lds, const float2* spill, int t,
    const float* __restrict__ yat, float* __restrict__ out, int p)
{
  const float* W1t = lds;
  const float* W2t = lds + 320;
  const float* W3t = lds + 576;
  const float* sb1 = lds + 1088;
  const float* sb2 = lds + 1104;
  const float* sb3 = lds + 1120;
  const float* S1 = lds + 1136;
  const float* T1 = lds + 1152;
  const float* S2 = lds + 1168;
  const float* T2 = lds + 1184;

  float fx1[16], fx2[16];
  #pragma unroll
  for (int o = 0; o < 16; ++o) { fx1[o] = 0.0f; fx2[o] = 0.0f; }

  #pragma unroll 1
  for (int j = 0; j < 16; ++j) {
    float2 sv = spill[j*256 + t];
    float invd = 1.0f / sv.x;
    int id = __float_as_int(sv.y);
    const float4* a4 = (const float4*)(yat + ((size_t)id << 4));
    float4 q0 = a4[0], q1 = a4[1], q2 = a4[2], q3 = a4[3];
    float a[16];
    a[0]=q0.x; a[1]=q0.y; a[2]=q0.z; a[3]=q0.w;
    a[4]=q1.x; a[5]=q1.y; a[6]=q1.z; a[7]=q1.w;
    a[8]=q2.x; a[9]=q2.y; a[10]=q2.z; a[11]=q2.w;
    a[12]=q3.x; a[13]=q3.y; a[14]=q3.z; a[15]=q3.w;
    float h[16];
    #pragma unroll
    for (int o = 0; o < 16; ++o) {
      float acc = fmaf(invd, W1t[o*20 + 16], sb1[o]);
      #pragma unroll
      for (int i = 0; i < 16; ++i) acc = fmaf(a[i], W1t[o*20 + i], acc);
      acc = fmaxf(acc, 0.2f * acc);
      float hv = fmaf(acc, S1[o], T1[o]);
      h[o] = hv;
      fx1[o] += hv;
    }
    #pragma unroll
    for (int o = 0; o < 16; ++o) {
      float acc = sb2[o];
      #pragma unroll
      for (int i = 0; i < 16; ++i) acc = fmaf(h[i], W2t[o*16 + i], acc);
      acc = fmaxf(acc, 0.2f * acc);
      fx2[o] += fmaf(acc, S2[o], T2[o]);
    }
  }

  float res[16];
  #pragma unroll
  for (int o = 0; o < 16; ++o) {
    float acc = sb3[o];
    #pragma unroll
    for (int i = 0; i < 16; ++i) acc = fmaf(fx1[i], W3t[o*32 + i], acc);
    #pragma unroll
    for (int i = 0; i < 16; ++i) acc = fmaf(fx2[i], W3t[o*32 + 16 + i], acc);
    res[o] = acc;
  }
  float* op = out + ((size_t)p << 4);
  float4 r;
  r.x=res[0]; r.y=res[1]; r.z=res[2]; r.w=res[3];   ((float4*)op)[0] = r;
  r.x=res[4]; r.y=res[5]; r.z=res[6]; r.w=res[7];   ((float4*)op)[1] = r;
  r.x=res[8]; r.y=res[9]; r.z=res[10]; r.w=res[11]; ((float4*)op)[2] = r;
  r.x=res[12]; r.y=res[13]; r.z=res[14]; r.w=res[15];((float4*)op)[3] = r;
}

__global__ void __launch_bounds__(256) knn_mlp_fused_kernel(
    const float* __restrict__ x, const float* __restrict__ yat,
    const float* __restrict__ W1, const float* __restrict__ b1,
    const float* __restrict__ W2, const float* __restrict__ b2,
    const float* __restrict__ W3, const float* __restrict__ b3,
    const float* __restrict__ g1, const float* __restrict__ be1,
    const float* __restrict__ m1, const float* __restrict__ v1,
    const float* __restrict__ g2, const float* __restrict__ be2,
    const float* __restrict__ m2, const float* __restrict__ v2,
    const float4* __restrict__ ys4, const int* __restrict__ ystart,
    const int* __restrict__ xorder, float* __restrict__ out)
{
  __shared__ float lds[1200];
  __shared__ float2 spill[4096];
  int t = threadIdx.x;
  stage_weights(lds, t, W1,b1,W2,b2,W3,b3, g1,be1,m1,v1, g2,be2,m2,v2);
  __syncthreads();

  int gid = blockIdx.x * 256 + t;
  int p = xorder[gid];
  float xpx = x[3*p], xpy = x[3*p+1], xpz = x[3*p+2];
  int cx = cell_coord(xpx), cy = cell_coord(xpy), cz = cell_coord(xpz);

  float s[16]; int si[16];
  #pragma unroll
  for (int j = 0; j < 16; ++j) { s[j] = BIGF; si[j] = 0; }

  auto scan_row = [&](int gz, int gy, int xa, int xb) {
    int rowbase = (gz*NC + gy)*NC;
    int r0 = ystart[rowbase + xa];
    int r1 = ystart[rowbase + xb + 1];
    for (int i = r0; i < r1; ++i) {
      float4 q = ys4[i];
      float dx = xpx - q.x, dy = xpy - q.y, dz = xpz - q.z;
      float d = fmaf(dx, dx, fmaf(dy, dy, dz*dz));
      if (d < s[15]) topk_insert(s, si, d, __float_as_int(q.w));
    }
  };

  {
    int z0 = cz-1 < 0 ? 0 : cz-1, z1 = cz+1 > NC-1 ? NC-1 : cz+1;
    int y0 = cy-1 < 0 ? 0 : cy-1, y1 = cy+1 > NC-1 ? NC-1 : cy+1;
    int x0 = cx-1 < 0 ? 0 : cx-1, x1 = cx+1 > NC-1 ? NC-1 : cx+1;
    for (int gz = z0; gz <= z1; ++gz)
      for (int gy = y0; gy <= y1; ++gy)
        scan_row(gz, gy, x0, x1);
  }

  int R = 1;
  while (true) {
    float b = BIGF;
    if (cx - R >= 0)    b = fminf(b, xpx - (float)(cx-R)*CELLW);
    if (cx + R <= NC-2) b = fminf(b, (float)(cx+R+1)*CELLW - xpx);
    if (cy - R >= 0)    b = fminf(b, xpy - (float)(cy-R)*CELLW);
    if (cy + R <= NC-2) b = fminf(b, (float)(cy+R+1)*CELLW - xpy);
    if (cz - R >= 0)    b = fminf(b, xpz - (float)(cz-R)*CELLW);
    if (cz + R <= NC-2) b = fminf(b, (float)(cz+R+1)*CELLW - xpz);
    b = fmaxf(b - 1e-4f, 0.0f);
    if (s[15] <= b*b || R >= NC) break;
    ++R;
    int z0 = cz-R < 0 ? 0 : cz-R, z1 = cz+R > NC-1 ? NC-1 : cz+R;
    int y0 = cy-R < 0 ? 0 : cy-R, y1 = cy+R > NC-1 ? NC-1 : cy+R;
    int x0 = cx-R < 0 ? 0 : cx-R, x1 = cx+R > NC-1 ? NC-1 : cx+R;
    for (int gz = z0; gz <= z1; ++gz) {
      int dzz = gz - cz; if (dzz < 0) dzz = -dzz;
      for (int gy = y0; gy <= y1; ++gy) {
        int dyy = gy - cy; if (dyy < 0) dyy = -dyy;
        if (dzz == R || dyy == R) {
          scan_row(gz, gy, x0, x1);
        } else {
          if (cx - R >= 0)    scan_row(gz, gy, cx-R, cx-R);
          if (cx + R <= NC-1) scan_row(gz, gy, cx+R, cx+R);
        }
      }
    }
  }

  #pragma unroll
  for (int j = 0; j < 16; ++j) spill[j*256 + t] = make_float2(s[j], __int_as_float(si[j]));
  mlp_and_store(lds, spill, t, yat, out, p);
}

// ---- fallback 2: brute force (no workspace needed) ----
__global__ void __launch_bounds__(256) brute_kernel(
    const float* __restrict__ x, const float* __restrict__ y, const float* __restrict__ yat,
    const float* __restrict__ W1, const float* __restrict__ b1,
    const float* __restrict__ W2, const float* __restrict__ b2,
    const float* __restrict__ W3, const float* __restrict__ b3,
    const float* __restrict__ g1, const float* __restrict__ be1,
    const float* __restrict__ m1, const float* __restrict__ v1,
    const float* __restrict__ g2, const float* __restrict__ be2,
    const float* __restrict__ m2, const float* __restrict__ v2,
    float* __restrict__ out)
{
  __shared__ float lds[1200];
  __shared__ float2 spill[4096];
  __shared__ float4 ybuf[1024];
  int t = threadIdx.x;
  stage_weights(lds, t, W1,b1,W2,b2,W3,b3, g1,be1,m1,v1, g2,be2,m2,v2);

  int gid = blockIdx.x * 256 + t;
  float xpx = x[3*gid], xpy = x[3*gid+1], xpz = x[3*gid+2];
  float s[16]; int si[16];
  #pragma unroll
  for (int j = 0; j < 16; ++j) { s[j] = BIGF; si[j] = 0; }

  for (int base = 0; base < M_PTS; base += 1024) {
    int nload = M_PTS - base; if (nload > 1024) nload = 1024;
    __syncthreads();
    for (int k = t; k < nload; k += 256) {
      int i = base + k;
      ybuf[k] = make_float4(y[3*i], y[3*i+1], y[3*i+2], __int_as_float(i));
    }
    __syncthreads();
    for (int i2 = 0; i2 < nload; ++i2) {
      float4 q = ybuf[i2];
      float dx = xpx - q.x, dy = xpy - q.y, dz = xpz - q.z;
      float d = fmaf(dx, dx, fmaf(dy, dy, dz*dz));
      if (d < s[15]) topk_insert(s, si, d, __float_as_int(q.w));
    }
  }

  #pragma unroll
  for (int j = 0; j < 16; ++j) spill[j*256 + t] = make_float2(s[j], __int_as_float(si[j]));
  mlp_and_store(lds, spill, t, yat, out, gid);
}

extern "C" void kernel_launch(void* const* d_in, const int* in_sizes, int n_in,
                              void* d_out, int out_size, void* d_ws, size_t ws_size,
                              hipStream_t stream) {
  const float* x   = (const float*)d_in[0];
  const float* y   = (const float*)d_in[1];
  const float* yat = (const float*)d_in[2];
  const float* W1  = (const float*)d_in[5];
  const float* b1  = (const float*)d_in[6];
  const float* W2  = (const float*)d_in[7];
  const float* b2  = (const float*)d_in[8];
  const float* W3  = (const float*)d_in[9];
  const float* b3  = (const float*)d_in[10];
  const float* g1  = (const float*)d_in[11];
  const float* be1 = (const float*)d_in[12];
  const float* m1  = (const float*)d_in[13];
  const float* v1  = (const float*)d_in[14];
  const float* g2  = (const float*)d_in[15];
  const float* be2 = (const float*)d_in[16];
  const float* m2  = (const float*)d_in[17];
  const float* v2  = (const float*)d_in[18];
  float* out = (float*)d_out;

  // split-path ws layout (bytes):
  //   ys4    @ 0       : 320000
  //   xs4    @ 320000  : 1310720   (N float4: coords + orig idx)
  //   xorder @ 1630720 : 327680
  //   pi     @ 1958400 : 2621440   (N*16 u16, [gid][j])
  //   ycnt   @ 4579840 : 8800
  //   xcnt   @ 4588640 : 8800
  //   ystart @ 4597440 : 8800
  //   ycur   @ 4606240 : 8800
  //   xstart @ 4615040 : 8800
  //   xcur   @ 4623840 : 8800      -> end 4632640
  const size_t WS_SPLIT = 4632640;
  const size_t WS_FUSED = 700480;

  if (ws_size >= WS_SPLIT) {
    char* ws = (char*)d_ws;
    float4* ys4 = (float4*)(ws);
    float4* xs4 = (float4*)(ws + 320000);
    int* xorder = (int*)(ws + 1630720);
    unsigned short* pi = (unsigned short*)(ws + 1958400);
    int* ycnt   = (int*)(ws + 4579840);
    int* xcnt   = (int*)(ws + 4588640);
    int* ystart = (int*)(ws + 4597440);
    int* ycur   = (int*)(ws + 4606240);
    int* xstart = (int*)(ws + 4615040);
    int* xcur   = (int*)(ws + 4623840);

    hipMemsetAsync(ws + 4579840, 0, 17600, stream);   // ycnt + xcnt
    int grid_mn = (M_PTS + N_PTS + 255) / 256;
    hist_both_kernel<<<grid_mn, 256, 0, stream>>>(y, x, ycnt, xcnt);
    scan2_kernel<<<2, 1024, 0, stream>>>(ycnt, ystart, ycur, xcnt, xstart, xcur);
    scatter_both_kernel<<<grid_mn, 256, 0, stream>>>(y, x, ycur, xcur, ys4, xorder, xs4);
    // no sortcell: key-space selection is scan-order independent
    knn_cell_kernel<<<NCELLS*2, 64, 0, stream>>>(xs4, ys4, ystart, xstart, pi);
    mlp_kernel<<<(N_PTS*16)/256, 256, 0, stream>>>(yat, xs4, y, W1,b1,W2,b2,W3,b3,
        g1,be1,m1,v1, g2,be2,m2,v2, pi, out);
  } else if (ws_size >= WS_FUSED) {
    char* ws = (char*)d_ws;
    float4* ys4 = (float4*)(ws);
    int* xorder = (int*)(ws + 320000);
    int* ycnt   = (int*)(ws + 647680);
    int* xcnt   = (int*)(ws + 656480);
    int* ystart = (int*)(ws + 665280);
    int* ycur   = (int*)(ws + 674080);
    int* xstart = (int*)(ws + 682880);
    int* xcur   = (int*)(ws + 691680);

    hipMemsetAsync(ws + 647680, 0, 17588, stream);
    int grid_mn = (M_PTS + N_PTS + 255) / 256;
    hist_both_kernel<<<grid_mn, 256, 0, stream>>>(y, x, ycnt, xcnt);
    scan2_kernel<<<2, 1024, 0, stream>>>(ycnt, ystart, ycur, xcnt, xstart, xcur);
    scatter_both_kernel<<<grid_mn, 256, 0, stream>>>(y, x, ycur, xcur, ys4, xorder, nullptr);
    sortcell_kernel<<<(NCELLS+255)/256, 256, 0, stream>>>(ys4, ystart);
    knn_mlp_fused_kernel<<<N_PTS/256, 256, 0, stream>>>(x, yat, W1,b1,W2,b2,W3,b3,
        g1,be1,m1,v1, g2,be2,m2,v2, ys4, ystart, xorder, out);
  } else {
    brute_kernel<<<N_PTS/256, 256, 0, stream>>>(x, y, yat, W1,b1,W2,b2,W3,b3,
        g1,be1,m1,v1, g2,be2,m2,v2, out);
  }
}